// Round 1
// baseline (7991.957 us; speedup 1.0000x reference)
//
#include <hip/hip_runtime.h>
#include <cstdint>

typedef unsigned short u16;
typedef __attribute__((ext_vector_type(8))) short bf16x8;
typedef __attribute__((ext_vector_type(4))) float f32x4;

#define B_SZ 32
#define NTOK 384
#define DIM 768
#define NH 12
#define HD 64
#define MLP 3072
#define MROWS (B_SZ * NTOK) /* 12288 */

__device__ __forceinline__ float b2f(u16 h) { return __uint_as_float(((unsigned)h) << 16); }
__device__ __forceinline__ u16 f2b(float f) {
    unsigned u = __float_as_uint(f);
    unsigned r = u + 0x7fffu + ((u >> 16) & 1u); // RNE
    return (u16)(r >> 16);
}

__device__ __forceinline__ void load_lds16(const void* g, void* l) {
    __builtin_amdgcn_global_load_lds(
        (const __attribute__((address_space(1))) unsigned*)g,
        (__attribute__((address_space(3))) unsigned*)l, 16, 0, 0);
}

// ---------------- dtype detect: bf16 vs f32 storage of inputs ----------------
__global__ void detect_kernel(const u16* __restrict__ x, int* __restrict__ flagp) {
    __shared__ int cnt;
    if (threadIdx.x == 0) cnt = 0;
    __syncthreads();
    int bad = 0;
    for (int i = threadIdx.x; i < 4096; i += 256) {
        int e = (x[i] >> 7) & 0xFF;
        if (e >= 0xC0) bad++;
    }
    atomicAdd(&cnt, bad);
    __syncthreads();
    if (threadIdx.x == 0) *flagp = (cnt > 4) ? 1 : 0;
}

__global__ void conv_any(const void* __restrict__ src, u16* __restrict__ dst, int n,
                         const int* __restrict__ flagp) {
    int i = blockIdx.x * 256 + threadIdx.x;
    if (i >= n) return;
    dst[i] = (*flagp) ? f2b(((const float*)src)[i]) : ((const u16*)src)[i];
}

__global__ void load_x(const void* __restrict__ src, float* __restrict__ dst, int n,
                       const int* __restrict__ flagp) {
    int i = blockIdx.x * 256 + threadIdx.x;
    if (i >= n) return;
    dst[i] = (*flagp) ? ((const float*)src)[i] : b2f(((const u16*)src)[i]);
}

__global__ void store_out(const float* __restrict__ src, void* __restrict__ dst, int n,
                          const int* __restrict__ flagp) {
    int i = blockIdx.x * 256 + threadIdx.x;
    if (i >= n) return;
    if (*flagp) ((float*)dst)[i] = src[i];
    else ((u16*)dst)[i] = f2b(src[i]);
}

// ---------------- dual-dtype weight transpose: in[K,N](+elem off) -> out[N,K] bf16 ----
__global__ __launch_bounds__(256) void transpose_k(const void* __restrict__ in, size_t ioff,
                                                   u16* __restrict__ outp, int K, int N,
                                                   const int* __restrict__ flagp) {
    __shared__ u16 t[32][33];
    const int flag = *flagp;
    const int n0 = blockIdx.x << 5, k0 = blockIdx.y << 5;
    const int tx = threadIdx.x, ty = threadIdx.y;
#pragma unroll
    for (int i = 0; i < 4; i++) {
        size_t idx = ioff + (size_t)(k0 + ty + i * 8) * N + n0 + tx;
        t[ty + i * 8][tx] = flag ? f2b(((const float*)in)[idx]) : ((const u16*)in)[idx];
    }
    __syncthreads();
#pragma unroll
    for (int i = 0; i < 4; i++)
        outp[(size_t)(n0 + ty + i * 8) * K + k0 + tx] = t[tx][ty + i * 8];
}

// ---------------- bf16 GEMM, double-buffered 2-phase: C[M,N] = A[M,K] * Bt[N,K]^T + bias --
// MODE 0: store bf16. MODE 1: bias+GELU(exact), store bf16. MODE 2: f32 residual += (bias+val).
// SPLITK>1 (MODE 2 only): blockIdx.z selects K-chunk; partial sums via atomicAdd, bias on z==0.
// LDS read addresses XOR-swizzled (seg ^= row&3) with matching pre-swizzled global source
// (global_load_lds dest must stay linear - rule 21), cutting 8-way ds_read conflicts to 4-way.
template <int MODE, int SPLITK>
__global__ __launch_bounds__(256) void gemm_bt(const u16* __restrict__ A,
                                               const u16* __restrict__ Bt,
                                               const u16* __restrict__ bias,
                                               u16* __restrict__ outb,
                                               float* __restrict__ outf,
                                               int N, int K) {
    __shared__ u16 lA[2][128 * 32];
    __shared__ u16 lB[2][128 * 32];
    const int tid = threadIdx.x;
    const int wave = tid >> 6, lane = tid & 63;
    const int quad = lane >> 4, l16 = lane & 15;

    // XCD-aware bijective block remap (T1/m204): consecutive logical tiles -> same XCD L2.
    const int gx = gridDim.x;
    const int nwg = gx * gridDim.y;
    const int orig = blockIdx.y * gx + blockIdx.x;
    const int xcd = orig & 7, loc = orig >> 3;
    const int qq = nwg >> 3, rr = nwg & 7;
    const int wgid = (xcd < rr ? xcd * (qq + 1) : rr * (qq + 1) + (xcd - rr) * qq) + loc;
    const int bx = wgid % gx, by = wgid / gx;

    const int m0 = by << 7, n0 = bx << 7;
    const int wm = (wave & 1) << 6, wn = (wave >> 1) << 6;
    const int arow = lane >> 2;
    const int aseg = (((lane & 3) ^ (arow & 3)) << 3);  // pre-swizzled source segment

    const int KC = K / SPLITK;
    const int kBase = (SPLITK > 1) ? (int)blockIdx.z * KC : 0;

    f32x4 acc[4][4] = {};

    const u16* gA = A + (size_t)(m0 + wave * 16 + arow) * K + kBase + aseg;
    const u16* gB = Bt + (size_t)(n0 + wave * 16 + arow) * K + kBase + aseg;
    const size_t skip = (size_t)64 * K; // +4 row-groups

#define STAGE(buf, kt)                                                          \
    do {                                                                        \
        load_lds16(gA + (kt), &lA[buf][wave * 512 + lane * 8]);                 \
        load_lds16(gA + (kt) + skip, &lA[buf][(wave + 4) * 512 + lane * 8]);    \
        load_lds16(gB + (kt), &lB[buf][wave * 512 + lane * 8]);                 \
        load_lds16(gB + (kt) + skip, &lB[buf][(wave + 4) * 512 + lane * 8]);    \
    } while (0)

    STAGE(0, 0);
    __syncthreads();  // vmcnt(0) drain + barrier: buf0 ready
    int cur = 0;
    for (int kt = 0; kt < KC; kt += 32) {
        const int nxt = kt + 32;
        if (nxt < KC) STAGE(cur ^ 1, nxt);  // prefetch overlaps ds_read+MFMA below
        bf16x8 af[4], bfr[4];
#pragma unroll
        for (int i = 0; i < 4; i++) {
            const int ra = wm + i * 16 + l16;
            const int rb = wn + i * 16 + l16;
            af[i] = *(const bf16x8*)&lA[cur][ra * 32 + ((quad ^ (l16 & 3)) << 3)];
            bfr[i] = *(const bf16x8*)&lB[cur][rb * 32 + ((quad ^ (l16 & 3)) << 3)];
        }
#pragma unroll
        for (int i = 0; i < 4; i++)
#pragma unroll
            for (int j = 0; j < 4; j++)
                acc[i][j] = __builtin_amdgcn_mfma_f32_16x16x32_bf16(af[i], bfr[j], acc[i][j], 0, 0, 0);
        if (nxt < KC) {
            __syncthreads();  // drains prefetch (vmcnt) + all ds_reads of cur (lgkmcnt)
            cur ^= 1;
        }
    }
#undef STAGE

    const bool addb = (SPLITK == 1) || (blockIdx.z == 0);
#pragma unroll
    for (int j = 0; j < 4; j++) {
        const int n = n0 + wn + j * 16 + l16;
        const float bv = addb ? b2f(bias[n]) : 0.f;
#pragma unroll
        for (int i = 0; i < 4; i++) {
            const int mrow = m0 + wm + i * 16 + quad * 4;
#pragma unroll
            for (int r = 0; r < 4; r++) {
                float v = acc[i][j][r] + bv;
                size_t idx = (size_t)(mrow + r) * N + n;
                if (MODE == 0) {
                    outb[idx] = f2b(v);
                } else if (MODE == 1) {
                    float t = 0.5f * v * (1.0f + erff(v * 0.70710678118654752f));
                    outb[idx] = f2b(t);
                } else {
                    if (SPLITK == 1) outf[idx] += v;
                    else atomicAdd(&outf[idx], v);
                }
            }
        }
    }
}

// ---------------- LayerNorm: f32 in -> bf16 out, one wave per row ----------------
__global__ __launch_bounds__(256) void ln_kernel(const float* __restrict__ x,
                                                 const u16* __restrict__ g,
                                                 const u16* __restrict__ bta,
                                                 u16* __restrict__ y) {
    const int wave = threadIdx.x >> 6, lane = threadIdx.x & 63;
    const int row = (blockIdx.x << 2) + wave;
    const float4* xr = (const float4*)(x + (size_t)row * DIM);
    float4 v[3];
    float s = 0.f, sq = 0.f;
#pragma unroll
    for (int i = 0; i < 3; i++) {
        v[i] = xr[i * 64 + lane];
        s += v[i].x + v[i].y + v[i].z + v[i].w;
        sq += v[i].x * v[i].x + v[i].y * v[i].y + v[i].z * v[i].z + v[i].w * v[i].w;
    }
#pragma unroll
    for (int off = 32; off >= 1; off >>= 1) {
        s += __shfl_xor(s, off, 64);
        sq += __shfl_xor(sq, off, 64);
    }
    const float mean = s * (1.f / DIM);
    const float var = sq * (1.f / DIM) - mean * mean;
    const float rs = rsqrtf(var + 1e-5f);
    u16* yr = y + (size_t)row * DIM;
#pragma unroll
    for (int i = 0; i < 3; i++) {
        ushort4 gg = ((const ushort4*)g)[i * 64 + lane];
        ushort4 bb = ((const ushort4*)bta)[i * 64 + lane];
        ushort4 o;
        o.x = f2b((v[i].x - mean) * rs * b2f(gg.x) + b2f(bb.x));
        o.y = f2b((v[i].y - mean) * rs * b2f(gg.y) + b2f(bb.y));
        o.z = f2b((v[i].z - mean) * rs * b2f(gg.z) + b2f(bb.z));
        o.w = f2b((v[i].w - mean) * rs * b2f(gg.w) + b2f(bb.w));
        ((ushort4*)yr)[i * 64 + lane] = o;
    }
}

// ---------------- Attention: one block per (b_local, h, 64-query tile) ----------------
template <int NJ, int JLO>
__global__ __launch_bounds__(256) void attn_kernel(const u16* __restrict__ qkv,
                                                   u16* __restrict__ out) {
    __shared__ u16 vT[64 * 392];       // V^T [d][key], padded stride 392
    __shared__ u16 pbuf[4][16 * 72];   // per-wave P chunk [m][key%64], padded stride 72
    const int bx = blockIdx.x;
    const int qt = (NJ == 24) ? (bx + (bx >= 1 ? 1 : 0)) : 1;
    const int h = blockIdx.y, b = blockIdx.z;
    const int tid = threadIdx.x, wave = tid >> 6, lane = tid & 63;
    const int quad = lane >> 4, l16 = lane & 15;
    const u16* base = qkv + (size_t)b * NTOK * (3 * DIM);

    for (int it = tid; it < NTOK * 8; it += 256) {
        const int key = it >> 3, dseg = it & 7;
        const u16* gp = base + (size_t)key * (3 * DIM) + 2 * DIM + h * HD + dseg * 8;
        ushort4 u0 = ((const ushort4*)gp)[0];
        ushort4 u1 = ((const ushort4*)gp)[1];
        u16 vals[8] = {u0.x, u0.y, u0.z, u0.w, u1.x, u1.y, u1.z, u1.w};
#pragma unroll
        for (int t = 0; t < 8; t++) {
            const int i = (t + key) & 7;
            vT[(dseg * 8 + i) * 392 + key] = vals[i];
        }
    }

    bf16x8 qf[2];
    const int qrow = qt * 64 + wave * 16 + l16;
#pragma unroll
    for (int s = 0; s < 2; s++)
        qf[s] = *(const bf16x8*)(base + (size_t)qrow * (3 * DIM) + h * HD + s * 32 + quad * 8);

    __syncthreads();

    f32x4 sacc[NJ];
#pragma unroll
    for (int j = 0; j < NJ; j++) {
        const int key = (JLO + j) * 16 + l16;
        const u16* kb = base + (size_t)key * (3 * DIM) + DIM + h * HD;
        bf16x8 k0 = *(const bf16x8*)(kb + quad * 8);
        bf16x8 k1 = *(const bf16x8*)(kb + 32 + quad * 8);
        f32x4 z = {0.f, 0.f, 0.f, 0.f};
        z = __builtin_amdgcn_mfma_f32_16x16x32_bf16(qf[0], k0, z, 0, 0, 0);
        sacc[j] = __builtin_amdgcn_mfma_f32_16x16x32_bf16(qf[1], k1, z, 0, 0, 0);
    }

    float mx[4] = {-1e30f, -1e30f, -1e30f, -1e30f};
#pragma unroll
    for (int j = 0; j < NJ; j++)
#pragma unroll
        for (int r = 0; r < 4; r++) mx[r] = fmaxf(mx[r], sacc[j][r]);
#pragma unroll
    for (int off = 1; off < 16; off <<= 1)
#pragma unroll
        for (int r = 0; r < 4; r++) mx[r] = fmaxf(mx[r], __shfl_xor(mx[r], off, 64));

    float sm[4] = {0.f, 0.f, 0.f, 0.f};
#pragma unroll
    for (int j = 0; j < NJ; j++)
#pragma unroll
        for (int r = 0; r < 4; r++) {
            float e = __expf((sacc[j][r] - mx[r]) * 0.125f);
            sacc[j][r] = e;
            sm[r] += e;
        }
#pragma unroll
    for (int off = 1; off < 16; off <<= 1)
#pragma unroll
        for (int r = 0; r < 4; r++) sm[r] += __shfl_xor(sm[r], off, 64);
    float inv[4];
#pragma unroll
    for (int r = 0; r < 4; r++) inv[r] = 1.f / sm[r];

    f32x4 oacc[4] = {};
    u16* pb = &pbuf[wave][0];
#pragma unroll
    for (int c = 0; c < NJ / 4; c++) {
        __syncthreads();
#pragma unroll
        for (int jj = 0; jj < 4; jj++) {
#pragma unroll
            for (int r = 0; r < 4; r++)
                pb[(quad * 4 + r) * 72 + jj * 16 + l16] = f2b(sacc[c * 4 + jj][r] * inv[r]);
        }
        __syncthreads();
#pragma unroll
        for (int s = 0; s < 2; s++) {
            bf16x8 pf = *(const bf16x8*)&pb[l16 * 72 + s * 32 + quad * 8];
            const int kcol = JLO * 16 + c * 64 + s * 32 + quad * 8;
#pragma unroll
            for (int jd = 0; jd < 4; jd++) {
                bf16x8 vf = *(const bf16x8*)&vT[(jd * 16 + l16) * 392 + kcol];
                oacc[jd] = __builtin_amdgcn_mfma_f32_16x16x32_bf16(pf, vf, oacc[jd], 0, 0, 0);
            }
        }
    }

    const int q = qt * 64 + wave * 16 + quad * 4;
    u16* orow = out + (size_t)(b * NTOK + q) * DIM + h * HD;
#pragma unroll
    for (int jd = 0; jd < 4; jd++)
#pragma unroll
        for (int r = 0; r < 4; r++)
            orow[(size_t)r * DIM + jd * 16 + l16] = f2b(oacc[jd][r]);
}

extern "C" void kernel_launch(void* const* d_in, const int* in_sizes, int n_in,
                              void* d_out, int out_size, void* d_ws, size_t ws_size,
                              hipStream_t stream) {
    const void* x_in   = d_in[0];
    const void* qkv_w  = d_in[1];
    const void* qkv_b  = d_in[2];
    const void* proj_w = d_in[3];
    const void* proj_b = d_in[4];
    const void* ln1_g  = d_in[5];
    const void* ln1_b  = d_in[6];
    const void* ln2_g  = d_in[7];
    const void* ln2_b  = d_in[8];
    const void* fc1_w  = d_in[9];
    const void* fc1_b  = d_in[10];
    const void* fc2_w  = d_in[11];
    const void* fc2_b  = d_in[12];

    constexpr size_t SZ_X32 = (size_t)MROWS * DIM * 4;      // 37,748,736
    constexpr size_t SZ_ABUF = (size_t)MROWS * DIM * 2;     // 18,874,368
    constexpr size_t SZ_BIG = (size_t)MROWS * MLP * 2;      // 75,497,472
    constexpr size_t SZ_WT = (size_t)(2304 * 768 + 768 * 768 + 3072 * 768 + 768 * 3072) * 2;
    constexpr size_t SZ_PAR = 262144;
    const size_t fixed = SZ_X32 + SZ_ABUF + SZ_WT + SZ_PAR + 256;

    int nc;
    if (fixed + SZ_BIG <= ws_size) nc = 1;
    else if (fixed + SZ_BIG / 2 <= ws_size) nc = 2;
    else nc = 4;
    const size_t bigsz = SZ_BIG / nc;

    char* ws = (char*)d_ws;
    float* x32 = (float*)ws;
    u16* abuf = (u16*)(ws + SZ_X32);
    u16* big = (u16*)(ws + SZ_X32 + SZ_ABUF);
    u16* wqt = (u16*)(ws + SZ_X32 + SZ_ABUF + bigsz);
    u16* wpt = wqt + 2304 * 768;
    u16* w1t = wpt + 768 * 768;
    u16* w2t = w1t + 3072 * 768;
    u16* par = w2t + 768 * 3072;
    int* flagp = (int*)((char*)(par) + SZ_PAR);

    u16* p_qkvb = par;
    u16* p_projb = p_qkvb + 12 * 2304;
    u16* p_ln1g = p_projb + 12 * 768;
    u16* p_ln1b = p_ln1g + 12 * 768;
    u16* p_ln2g = p_ln1b + 12 * 768;
    u16* p_ln2b = p_ln2g + 12 * 768;
    u16* p_fc1b = p_ln2b + 12 * 768;
    u16* p_fc2b = p_fc1b + 12 * 3072;

    const int NEL = MROWS * DIM;
    detect_kernel<<<1, 256, 0, stream>>>((const u16*)x_in, flagp);
    load_x<<<(NEL + 255) / 256, 256, 0, stream>>>(x_in, x32, NEL, flagp);
    conv_any<<<(12 * 2304 + 255) / 256, 256, 0, stream>>>(qkv_b, p_qkvb, 12 * 2304, flagp);
    conv_any<<<(12 * 768 + 255) / 256, 256, 0, stream>>>(proj_b, p_projb, 12 * 768, flagp);
    conv_any<<<(12 * 768 + 255) / 256, 256, 0, stream>>>(ln1_g, p_ln1g, 12 * 768, flagp);
    conv_any<<<(12 * 768 + 255) / 256, 256, 0, stream>>>(ln1_b, p_ln1b, 12 * 768, flagp);
    conv_any<<<(12 * 768 + 255) / 256, 256, 0, stream>>>(ln2_g, p_ln2g, 12 * 768, flagp);
    conv_any<<<(12 * 768 + 255) / 256, 256, 0, stream>>>(ln2_b, p_ln2b, 12 * 768, flagp);
    conv_any<<<(12 * 3072 + 255) / 256, 256, 0, stream>>>(fc1_b, p_fc1b, 12 * 3072, flagp);
    conv_any<<<(12 * 768 + 255) / 256, 256, 0, stream>>>(fc2_b, p_fc2b, 12 * 768, flagp);

    const int CR = MROWS / nc;  // rows per chunk (multiple of 128)
    const int CB = B_SZ / nc;   // batches per chunk

    for (int l = 0; l < 12; l++) {
        transpose_k<<<dim3(2304 / 32, 768 / 32), dim3(32, 8), 0, stream>>>(
            qkv_w, (size_t)l * DIM * 2304, wqt, DIM, 2304, flagp);
        transpose_k<<<dim3(768 / 32, 768 / 32), dim3(32, 8), 0, stream>>>(
            proj_w, (size_t)l * DIM * DIM, wpt, DIM, DIM, flagp);
        transpose_k<<<dim3(3072 / 32, 768 / 32), dim3(32, 8), 0, stream>>>(
            fc1_w, (size_t)l * DIM * MLP, w1t, DIM, MLP, flagp);
        transpose_k<<<dim3(768 / 32, 3072 / 32), dim3(32, 8), 0, stream>>>(
            fc2_w, (size_t)l * MLP * DIM, w2t, MLP, DIM, flagp);

        for (int c = 0; c < nc; c++) {
            const size_t r0 = (size_t)c * CR;
            ln_kernel<<<CR / 4, 256, 0, stream>>>(x32 + r0 * DIM, p_ln1g + l * DIM,
                                                  p_ln1b + l * DIM, abuf + r0 * DIM);
            gemm_bt<0, 1><<<dim3(2304 / 128, CR / 128), 256, 0, stream>>>(
                abuf + r0 * DIM, wqt, p_qkvb + l * 2304, big, nullptr, 2304, DIM);
            attn_kernel<24, 0><<<dim3(5, NH, CB), 256, 0, stream>>>(big, abuf + r0 * DIM);
            attn_kernel<4, 4><<<dim3(1, NH, CB), 256, 0, stream>>>(big, abuf + r0 * DIM);
            gemm_bt<2, 2><<<dim3(DIM / 128, CR / 128, 2), 256, 0, stream>>>(
                abuf + r0 * DIM, wpt, p_projb + l * DIM, nullptr, x32 + r0 * DIM, DIM, DIM);
        }
        for (int c = 0; c < nc; c++) {
            const size_t r0 = (size_t)c * CR;
            ln_kernel<<<CR / 4, 256, 0, stream>>>(x32 + r0 * DIM, p_ln2g + l * DIM,
                                                  p_ln2b + l * DIM, abuf + r0 * DIM);
            gemm_bt<1, 1><<<dim3(MLP / 128, CR / 128), 256, 0, stream>>>(
                abuf + r0 * DIM, w1t, p_fc1b + l * MLP, big, nullptr, MLP, DIM);
            gemm_bt<2, 2><<<dim3(DIM / 128, CR / 128, 2), 256, 0, stream>>>(
                big, w2t, p_fc2b + l * DIM, nullptr, x32 + r0 * DIM, DIM, MLP);
        }
    }
    store_out<<<(NEL + 255) / 256, 256, 0, stream>>>(x32, d_out, NEL, flagp);
}

// Round 2
// 7411.731 us; speedup vs baseline: 1.0783x; 1.0783x over previous
//
#include <hip/hip_runtime.h>
#include <cstdint>

typedef unsigned short u16;
typedef __attribute__((ext_vector_type(8))) short bf16x8;
typedef __attribute__((ext_vector_type(4))) float f32x4;

#define B_SZ 32
#define NTOK 384
#define DIM 768
#define NH 12
#define HD 64
#define MLP 3072
#define MROWS (B_SZ * NTOK) /* 12288 */

__device__ __forceinline__ float b2f(u16 h) { return __uint_as_float(((unsigned)h) << 16); }
__device__ __forceinline__ u16 f2b(float f) {
    unsigned u = __float_as_uint(f);
    unsigned r = u + 0x7fffu + ((u >> 16) & 1u); // RNE
    return (u16)(r >> 16);
}

__device__ __forceinline__ void load_lds16(const void* g, void* l) {
    __builtin_amdgcn_global_load_lds(
        (const __attribute__((address_space(1))) unsigned*)g,
        (__attribute__((address_space(3))) unsigned*)l, 16, 0, 0);
}

// ---------------- dtype detect: bf16 vs f32 storage of inputs ----------------
__global__ void detect_kernel(const u16* __restrict__ x, int* __restrict__ flagp) {
    __shared__ int cnt;
    if (threadIdx.x == 0) cnt = 0;
    __syncthreads();
    int bad = 0;
    for (int i = threadIdx.x; i < 4096; i += 256) {
        int e = (x[i] >> 7) & 0xFF;
        if (e >= 0xC0) bad++;
    }
    atomicAdd(&cnt, bad);
    __syncthreads();
    if (threadIdx.x == 0) *flagp = (cnt > 4) ? 1 : 0;
}

__global__ void conv_any(const void* __restrict__ src, u16* __restrict__ dst, int n,
                         const int* __restrict__ flagp) {
    int i = blockIdx.x * 256 + threadIdx.x;
    if (i >= n) return;
    dst[i] = (*flagp) ? f2b(((const float*)src)[i]) : ((const u16*)src)[i];
}

__global__ void load_x(const void* __restrict__ src, float* __restrict__ dst, int n,
                       const int* __restrict__ flagp) {
    int i = blockIdx.x * 256 + threadIdx.x;
    if (i >= n) return;
    dst[i] = (*flagp) ? ((const float*)src)[i] : b2f(((const u16*)src)[i]);
}

__global__ void store_out(const float* __restrict__ src, void* __restrict__ dst, int n,
                          const int* __restrict__ flagp) {
    int i = blockIdx.x * 256 + threadIdx.x;
    if (i >= n) return;
    if (*flagp) ((float*)dst)[i] = src[i];
    else ((u16*)dst)[i] = f2b(src[i]);
}

// ---------------- dual-dtype weight transpose: in[K,N](+elem off) -> out[N,K] bf16 ----
__global__ __launch_bounds__(256) void transpose_k(const void* __restrict__ in, size_t ioff,
                                                   u16* __restrict__ outp, int K, int N,
                                                   const int* __restrict__ flagp) {
    __shared__ u16 t[32][33];
    const int flag = *flagp;
    const int n0 = blockIdx.x << 5, k0 = blockIdx.y << 5;
    const int tx = threadIdx.x, ty = threadIdx.y;
#pragma unroll
    for (int i = 0; i < 4; i++) {
        size_t idx = ioff + (size_t)(k0 + ty + i * 8) * N + n0 + tx;
        t[ty + i * 8][tx] = flag ? f2b(((const float*)in)[idx]) : ((const u16*)in)[idx];
    }
    __syncthreads();
#pragma unroll
    for (int i = 0; i < 4; i++)
        outp[(size_t)(n0 + ty + i * 8) * K + k0 + tx] = t[tx][ty + i * 8];
}

// ---------------- bf16 GEMM, T3-minimum 2-phase pipeline: C = A[M,K] * Bt[N,K]^T + bias --
// Tile TM x 128, BK=32, 4 waves (2x2), double-buffered LDS. Per iter: STAGE(next) issued
// BEFORE ds_read+MFMA of current; single raw s_barrier per iter preceded by vmcnt(0) so the
// prefetch latency hides under compute (T3 "minimum 2-phase", m230/m248: ~660-680 TF on 128^2).
// TM=64 doubles the grid for the N=768 GEMMs (proj/FC2): 1152 blocks = 4.5/CU vs 2.25.
// MODE 0: store bf16. MODE 1: bias+GELU(exact), store bf16. MODE 2: f32 residual += (bias+val).
template <int MODE, int TM>
__global__ __launch_bounds__(256) void gemm_bt(const u16* __restrict__ A,
                                               const u16* __restrict__ Bt,
                                               const u16* __restrict__ bias,
                                               u16* __restrict__ outb,
                                               float* __restrict__ outf,
                                               int N, int K) {
    constexpr int MI = (TM == 128) ? 4 : 2;  // 16-row fragment repeats per wave in M
    __shared__ u16 lA[2][TM * 32];
    __shared__ u16 lB[2][128 * 32];
    const int tid = threadIdx.x;
    const int wave = tid >> 6, lane = tid & 63;
    const int quad = lane >> 4, l16 = lane & 15;

    // XCD-aware bijective block remap (T1/m204): consecutive logical tiles -> same XCD L2.
    const int gx = gridDim.x;
    const int nwg = gx * gridDim.y;
    const int orig = blockIdx.y * gx + blockIdx.x;
    const int xcd = orig & 7, loc = orig >> 3;
    const int qq = nwg >> 3, rr = nwg & 7;
    const int wgid = (xcd < rr ? xcd * (qq + 1) : rr * (qq + 1) + (xcd - rr) * qq) + loc;
    const int bx = wgid % gx, by = wgid / gx;

    const int m0 = by * TM, n0 = bx << 7;
    const int wm = (wave & 1) * (TM / 2), wn = (wave >> 1) << 6;
    const int arow = lane >> 2, aseg = (lane & 3) << 3;

    f32x4 acc[MI][4] = {};

    const u16* gA = A + (size_t)(m0 + wave * 16 + arow) * K + aseg;
    const u16* gB = Bt + (size_t)(n0 + wave * 16 + arow) * K + aseg;
    const size_t skip = (size_t)64 * K; // +4 row-groups

#define STAGE(buf, kt)                                                              \
    do {                                                                            \
        load_lds16(gA + (kt), &lA[buf][wave * 512 + lane * 8]);                     \
        if constexpr (TM == 128)                                                    \
            load_lds16(gA + (kt) + skip, &lA[buf][(wave + 4) * 512 + lane * 8]);    \
        load_lds16(gB + (kt), &lB[buf][wave * 512 + lane * 8]);                     \
        load_lds16(gB + (kt) + skip, &lB[buf][(wave + 4) * 512 + lane * 8]);        \
    } while (0)

    // prologue: fill buf0, full drain
    STAGE(0, 0);
    asm volatile("s_waitcnt vmcnt(0)" ::: "memory");
    __builtin_amdgcn_s_barrier();

    int cur = 0;
    for (int kt = 0; kt < K; kt += 32) {
        const bool more = (kt + 32 < K);
        if (more) STAGE(cur ^ 1, kt + 32);  // prefetch in flight across compute
        bf16x8 af[MI], bfr[4];
#pragma unroll
        for (int i = 0; i < MI; i++)
            af[i] = *(const bf16x8*)&lA[cur][(wm + i * 16 + l16) * 32 + quad * 8];
#pragma unroll
        for (int j = 0; j < 4; j++)
            bfr[j] = *(const bf16x8*)&lB[cur][(wn + j * 16 + l16) * 32 + quad * 8];
#pragma unroll
        for (int i = 0; i < MI; i++)
#pragma unroll
            for (int j = 0; j < 4; j++)
                acc[i][j] = __builtin_amdgcn_mfma_f32_16x16x32_bf16(af[i], bfr[j], acc[i][j], 0, 0, 0);
        if (more) {
            asm volatile("s_waitcnt vmcnt(0)" ::: "memory");  // prefetch landed (hidden under compute)
            __builtin_amdgcn_s_barrier();                     // all waves done reading cur
            cur ^= 1;
        }
    }
#undef STAGE

#pragma unroll
    for (int j = 0; j < 4; j++) {
        const int n = n0 + wn + j * 16 + l16;
        const float bv = b2f(bias[n]);
#pragma unroll
        for (int i = 0; i < MI; i++) {
            const int mrow = m0 + wm + i * 16 + quad * 4;
#pragma unroll
            for (int r = 0; r < 4; r++) {
                float v = acc[i][j][r] + bv;
                size_t idx = (size_t)(mrow + r) * N + n;
                if (MODE == 0) {
                    outb[idx] = f2b(v);
                } else if (MODE == 1) {
                    float t = 0.5f * v * (1.0f + erff(v * 0.70710678118654752f));
                    outb[idx] = f2b(t);
                } else {
                    outf[idx] += v;
                }
            }
        }
    }
}

// ---------------- LayerNorm: f32 in -> bf16 out, one wave per row ----------------
__global__ __launch_bounds__(256) void ln_kernel(const float* __restrict__ x,
                                                 const u16* __restrict__ g,
                                                 const u16* __restrict__ bta,
                                                 u16* __restrict__ y) {
    const int wave = threadIdx.x >> 6, lane = threadIdx.x & 63;
    const int row = (blockIdx.x << 2) + wave;
    const float4* xr = (const float4*)(x + (size_t)row * DIM);
    float4 v[3];
    float s = 0.f, sq = 0.f;
#pragma unroll
    for (int i = 0; i < 3; i++) {
        v[i] = xr[i * 64 + lane];
        s += v[i].x + v[i].y + v[i].z + v[i].w;
        sq += v[i].x * v[i].x + v[i].y * v[i].y + v[i].z * v[i].z + v[i].w * v[i].w;
    }
#pragma unroll
    for (int off = 32; off >= 1; off >>= 1) {
        s += __shfl_xor(s, off, 64);
        sq += __shfl_xor(sq, off, 64);
    }
    const float mean = s * (1.f / DIM);
    const float var = sq * (1.f / DIM) - mean * mean;
    const float rs = rsqrtf(var + 1e-5f);
    u16* yr = y + (size_t)row * DIM;
#pragma unroll
    for (int i = 0; i < 3; i++) {
        ushort4 gg = ((const ushort4*)g)[i * 64 + lane];
        ushort4 bb = ((const ushort4*)bta)[i * 64 + lane];
        ushort4 o;
        o.x = f2b((v[i].x - mean) * rs * b2f(gg.x) + b2f(bb.x));
        o.y = f2b((v[i].y - mean) * rs * b2f(gg.y) + b2f(bb.y));
        o.z = f2b((v[i].z - mean) * rs * b2f(gg.z) + b2f(bb.z));
        o.w = f2b((v[i].w - mean) * rs * b2f(gg.w) + b2f(bb.w));
        ((ushort4*)yr)[i * 64 + lane] = o;
    }
}

// ---------------- Attention: one block per (b_local, h, 64-query tile) ----------------
template <int NJ, int JLO>
__global__ __launch_bounds__(256) void attn_kernel(const u16* __restrict__ qkv,
                                                   u16* __restrict__ out) {
    __shared__ u16 vT[64 * 392];       // V^T [d][key], padded stride 392
    __shared__ u16 pbuf[4][16 * 72];   // per-wave P chunk [m][key%64], padded stride 72
    const int bx = blockIdx.x;
    const int qt = (NJ == 24) ? (bx + (bx >= 1 ? 1 : 0)) : 1;
    const int h = blockIdx.y, b = blockIdx.z;
    const int tid = threadIdx.x, wave = tid >> 6, lane = tid & 63;
    const int quad = lane >> 4, l16 = lane & 15;
    const u16* base = qkv + (size_t)b * NTOK * (3 * DIM);

    for (int it = tid; it < NTOK * 8; it += 256) {
        const int key = it >> 3, dseg = it & 7;
        const u16* gp = base + (size_t)key * (3 * DIM) + 2 * DIM + h * HD + dseg * 8;
        ushort4 u0 = ((const ushort4*)gp)[0];
        ushort4 u1 = ((const ushort4*)gp)[1];
        u16 vals[8] = {u0.x, u0.y, u0.z, u0.w, u1.x, u1.y, u1.z, u1.w};
#pragma unroll
        for (int t = 0; t < 8; t++) {
            const int i = (t + key) & 7;
            vT[(dseg * 8 + i) * 392 + key] = vals[i];
        }
    }

    bf16x8 qf[2];
    const int qrow = qt * 64 + wave * 16 + l16;
#pragma unroll
    for (int s = 0; s < 2; s++)
        qf[s] = *(const bf16x8*)(base + (size_t)qrow * (3 * DIM) + h * HD + s * 32 + quad * 8);

    __syncthreads();

    f32x4 sacc[NJ];
#pragma unroll
    for (int j = 0; j < NJ; j++) {
        const int key = (JLO + j) * 16 + l16;
        const u16* kb = base + (size_t)key * (3 * DIM) + DIM + h * HD;
        bf16x8 k0 = *(const bf16x8*)(kb + quad * 8);
        bf16x8 k1 = *(const bf16x8*)(kb + 32 + quad * 8);
        f32x4 z = {0.f, 0.f, 0.f, 0.f};
        z = __builtin_amdgcn_mfma_f32_16x16x32_bf16(qf[0], k0, z, 0, 0, 0);
        sacc[j] = __builtin_amdgcn_mfma_f32_16x16x32_bf16(qf[1], k1, z, 0, 0, 0);
    }

    float mx[4] = {-1e30f, -1e30f, -1e30f, -1e30f};
#pragma unroll
    for (int j = 0; j < NJ; j++)
#pragma unroll
        for (int r = 0; r < 4; r++) mx[r] = fmaxf(mx[r], sacc[j][r]);
#pragma unroll
    for (int off = 1; off < 16; off <<= 1)
#pragma unroll
        for (int r = 0; r < 4; r++) mx[r] = fmaxf(mx[r], __shfl_xor(mx[r], off, 64));

    float sm[4] = {0.f, 0.f, 0.f, 0.f};
#pragma unroll
    for (int j = 0; j < NJ; j++)
#pragma unroll
        for (int r = 0; r < 4; r++) {
            float e = __expf((sacc[j][r] - mx[r]) * 0.125f);
            sacc[j][r] = e;
            sm[r] += e;
        }
#pragma unroll
    for (int off = 1; off < 16; off <<= 1)
#pragma unroll
        for (int r = 0; r < 4; r++) sm[r] += __shfl_xor(sm[r], off, 64);
    float inv[4];
#pragma unroll
    for (int r = 0; r < 4; r++) inv[r] = 1.f / sm[r];

    f32x4 oacc[4] = {};
    u16* pb = &pbuf[wave][0];
#pragma unroll
    for (int c = 0; c < NJ / 4; c++) {
        __syncthreads();
#pragma unroll
        for (int jj = 0; jj < 4; jj++) {
#pragma unroll
            for (int r = 0; r < 4; r++)
                pb[(quad * 4 + r) * 72 + jj * 16 + l16] = f2b(sacc[c * 4 + jj][r] * inv[r]);
        }
        __syncthreads();
#pragma unroll
        for (int s = 0; s < 2; s++) {
            bf16x8 pf = *(const bf16x8*)&pb[l16 * 72 + s * 32 + quad * 8];
            const int kcol = JLO * 16 + c * 64 + s * 32 + quad * 8;
#pragma unroll
            for (int jd = 0; jd < 4; jd++) {
                bf16x8 vf = *(const bf16x8*)&vT[(jd * 16 + l16) * 392 + kcol];
                oacc[jd] = __builtin_amdgcn_mfma_f32_16x16x32_bf16(pf, vf, oacc[jd], 0, 0, 0);
            }
        }
    }

    const int q = qt * 64 + wave * 16 + quad * 4;
    u16* orow = out + (size_t)(b * NTOK + q) * DIM + h * HD;
#pragma unroll
    for (int jd = 0; jd < 4; jd++)
#pragma unroll
        for (int r = 0; r < 4; r++)
            orow[(size_t)r * DIM + jd * 16 + l16] = f2b(oacc[jd][r]);
}

extern "C" void kernel_launch(void* const* d_in, const int* in_sizes, int n_in,
                              void* d_out, int out_size, void* d_ws, size_t ws_size,
                              hipStream_t stream) {
    const void* x_in   = d_in[0];
    const void* qkv_w  = d_in[1];
    const void* qkv_b  = d_in[2];
    const void* proj_w = d_in[3];
    const void* proj_b = d_in[4];
    const void* ln1_g  = d_in[5];
    const void* ln1_b  = d_in[6];
    const void* ln2_g  = d_in[7];
    const void* ln2_b  = d_in[8];
    const void* fc1_w  = d_in[9];
    const void* fc1_b  = d_in[10];
    const void* fc2_w  = d_in[11];
    const void* fc2_b  = d_in[12];

    constexpr size_t SZ_X32 = (size_t)MROWS * DIM * 4;      // 37,748,736
    constexpr size_t SZ_ABUF = (size_t)MROWS * DIM * 2;     // 18,874,368
    constexpr size_t SZ_BIG = (size_t)MROWS * MLP * 2;      // 75,497,472
    constexpr size_t SZ_WT = (size_t)(2304 * 768 + 768 * 768 + 3072 * 768 + 768 * 3072) * 2;
    constexpr size_t SZ_PAR = 262144;
    const size_t fixed = SZ_X32 + SZ_ABUF + SZ_WT + SZ_PAR + 256;

    int nc;
    if (fixed + SZ_BIG <= ws_size) nc = 1;
    else if (fixed + SZ_BIG / 2 <= ws_size) nc = 2;
    else nc = 4;
    const size_t bigsz = SZ_BIG / nc;

    char* ws = (char*)d_ws;
    float* x32 = (float*)ws;
    u16* abuf = (u16*)(ws + SZ_X32);
    u16* big = (u16*)(ws + SZ_X32 + SZ_ABUF);
    u16* wqt = (u16*)(ws + SZ_X32 + SZ_ABUF + bigsz);
    u16* wpt = wqt + 2304 * 768;
    u16* w1t = wpt + 768 * 768;
    u16* w2t = w1t + 3072 * 768;
    u16* par = w2t + 768 * 3072;
    int* flagp = (int*)((char*)(par) + SZ_PAR);

    u16* p_qkvb = par;
    u16* p_projb = p_qkvb + 12 * 2304;
    u16* p_ln1g = p_projb + 12 * 768;
    u16* p_ln1b = p_ln1g + 12 * 768;
    u16* p_ln2g = p_ln1b + 12 * 768;
    u16* p_ln2b = p_ln2g + 12 * 768;
    u16* p_fc1b = p_ln2b + 12 * 768;
    u16* p_fc2b = p_fc1b + 12 * 3072;

    const int NEL = MROWS * DIM;
    detect_kernel<<<1, 256, 0, stream>>>((const u16*)x_in, flagp);
    load_x<<<(NEL + 255) / 256, 256, 0, stream>>>(x_in, x32, NEL, flagp);
    conv_any<<<(12 * 2304 + 255) / 256, 256, 0, stream>>>(qkv_b, p_qkvb, 12 * 2304, flagp);
    conv_any<<<(12 * 768 + 255) / 256, 256, 0, stream>>>(proj_b, p_projb, 12 * 768, flagp);
    conv_any<<<(12 * 768 + 255) / 256, 256, 0, stream>>>(ln1_g, p_ln1g, 12 * 768, flagp);
    conv_any<<<(12 * 768 + 255) / 256, 256, 0, stream>>>(ln1_b, p_ln1b, 12 * 768, flagp);
    conv_any<<<(12 * 768 + 255) / 256, 256, 0, stream>>>(ln2_g, p_ln2g, 12 * 768, flagp);
    conv_any<<<(12 * 768 + 255) / 256, 256, 0, stream>>>(ln2_b, p_ln2b, 12 * 768, flagp);
    conv_any<<<(12 * 3072 + 255) / 256, 256, 0, stream>>>(fc1_b, p_fc1b, 12 * 3072, flagp);
    conv_any<<<(12 * 768 + 255) / 256, 256, 0, stream>>>(fc2_b, p_fc2b, 12 * 768, flagp);

    const int CR = MROWS / nc;  // rows per chunk (multiple of 128)
    const int CB = B_SZ / nc;   // batches per chunk

    for (int l = 0; l < 12; l++) {
        transpose_k<<<dim3(2304 / 32, 768 / 32), dim3(32, 8), 0, stream>>>(
            qkv_w, (size_t)l * DIM * 2304, wqt, DIM, 2304, flagp);
        transpose_k<<<dim3(768 / 32, 768 / 32), dim3(32, 8), 0, stream>>>(
            proj_w, (size_t)l * DIM * DIM, wpt, DIM, DIM, flagp);
        transpose_k<<<dim3(3072 / 32, 768 / 32), dim3(32, 8), 0, stream>>>(
            fc1_w, (size_t)l * DIM * MLP, w1t, DIM, MLP, flagp);
        transpose_k<<<dim3(768 / 32, 3072 / 32), dim3(32, 8), 0, stream>>>(
            fc2_w, (size_t)l * MLP * DIM, w2t, MLP, DIM, flagp);

        for (int c = 0; c < nc; c++) {
            const size_t r0 = (size_t)c * CR;
            ln_kernel<<<CR / 4, 256, 0, stream>>>(x32 + r0 * DIM, p_ln1g + l * DIM,
                                                  p_ln1b + l * DIM, abuf + r0 * DIM);
            gemm_bt<0, 128><<<dim3(2304 / 128, CR / 128), 256, 0, stream>>>(
                abuf + r0 * DIM, wqt, p_qkvb + l * 2304, big, nullptr, 2304, DIM);
            attn_kernel<24, 0><<<dim3(5, NH, CB), 256, 0, stream>>>(big, abuf + r0 * DIM);
            attn_kernel<4, 4><<<dim3(1, NH, CB), 256, 0, stream>>>(big, abuf + r0 * DIM);
            gemm_bt<2, 64><<<dim3(DIM / 128, CR / 64), 256, 0, stream>>>(
                abuf + r0 * DIM, wpt, p_projb + l * DIM, nullptr, x32 + r0 * DIM, DIM, DIM);
        }
        for (int c = 0; c < nc; c++) {
            const size_t r0 = (size_t)c * CR;
            ln_kernel<<<CR / 4, 256, 0, stream>>>(x32 + r0 * DIM, p_ln2g + l * DIM,
                                                  p_ln2b + l * DIM, abuf + r0 * DIM);
            gemm_bt<1, 128><<<dim3(MLP / 128, CR / 128), 256, 0, stream>>>(
                abuf + r0 * DIM, w1t, p_fc1b + l * MLP, big, nullptr, MLP, DIM);
            gemm_bt<2, 64><<<dim3(DIM / 128, CR / 64), 256, 0, stream>>>(
                big, w2t, p_fc2b + l * DIM, nullptr, x32 + r0 * DIM, DIM, MLP);
        }
    }
    store_out<<<(NEL + 255) / 256, 256, 0, stream>>>(x32, d_out, NEL, flagp);
}

// Round 3
// 5760.323 us; speedup vs baseline: 1.3874x; 1.2867x over previous
//
#include <hip/hip_runtime.h>
#include <cstdint>

typedef unsigned short u16;
typedef __attribute__((ext_vector_type(8))) short bf16x8;
typedef __attribute__((ext_vector_type(4))) float f32x4;

#define B_SZ 32
#define NTOK 384
#define DIM 768
#define NH 12
#define HD 64
#define MLP 3072
#define MROWS (B_SZ * NTOK) /* 12288 */

__device__ __forceinline__ float b2f(u16 h) { return __uint_as_float(((unsigned)h) << 16); }
__device__ __forceinline__ u16 f2b(float f) {
    unsigned u = __float_as_uint(f);
    unsigned r = u + 0x7fffu + ((u >> 16) & 1u); // RNE
    return (u16)(r >> 16);
}

__device__ __forceinline__ void load_lds16(const void* g, void* l) {
    __builtin_amdgcn_global_load_lds(
        (const __attribute__((address_space(1))) unsigned*)g,
        (__attribute__((address_space(3))) unsigned*)l, 16, 0, 0);
}

// fast GELU: v * sigmoid(2*0.7978845608*(v + 0.044715 v^3)); overflow-safe both tails.
// |gelu_tanh - gelu_erf| <= ~3.6e-4, an order below bf16 ulp at |v|~2.
__device__ __forceinline__ float gelu_fast(float v) {
    float u2 = -1.5957691216f * v * (1.0f + 0.044715f * v * v);
    return v * __builtin_amdgcn_rcpf(1.0f + __expf(u2));
}

// ---------------- dtype detect: bf16 vs f32 storage of inputs ----------------
__global__ void detect_kernel(const u16* __restrict__ x, int* __restrict__ flagp) {
    __shared__ int cnt;
    if (threadIdx.x == 0) cnt = 0;
    __syncthreads();
    int bad = 0;
    for (int i = threadIdx.x; i < 4096; i += 256) {
        int e = (x[i] >> 7) & 0xFF;
        if (e >= 0xC0) bad++;
    }
    atomicAdd(&cnt, bad);
    __syncthreads();
    if (threadIdx.x == 0) *flagp = (cnt > 4) ? 1 : 0;
}

__global__ void conv_any(const void* __restrict__ src, u16* __restrict__ dst, int n,
                         const int* __restrict__ flagp) {
    int i = blockIdx.x * 256 + threadIdx.x;
    if (i >= n) return;
    dst[i] = (*flagp) ? f2b(((const float*)src)[i]) : ((const u16*)src)[i];
}

__global__ void load_x(const void* __restrict__ src, float* __restrict__ dst, int n,
                       const int* __restrict__ flagp) {
    int i = blockIdx.x * 256 + threadIdx.x;
    if (i >= n) return;
    dst[i] = (*flagp) ? ((const float*)src)[i] : b2f(((const u16*)src)[i]);
}

__global__ void store_out(const float* __restrict__ src, void* __restrict__ dst, int n,
                          const int* __restrict__ flagp) {
    int i = blockIdx.x * 256 + threadIdx.x;
    if (i >= n) return;
    if (*flagp) ((float*)dst)[i] = src[i];
    else ((u16*)dst)[i] = f2b(src[i]);
}

// ---------------- dual-dtype weight transpose: in[K,N](+elem off) -> out[N,K] bf16 ----
__global__ __launch_bounds__(256) void transpose_k(const void* __restrict__ in, size_t ioff,
                                                   u16* __restrict__ outp, int K, int N,
                                                   const int* __restrict__ flagp) {
    __shared__ u16 t[32][33];
    const int flag = *flagp;
    const int n0 = blockIdx.x << 5, k0 = blockIdx.y << 5;
    const int tx = threadIdx.x, ty = threadIdx.y;
#pragma unroll
    for (int i = 0; i < 4; i++) {
        size_t idx = ioff + (size_t)(k0 + ty + i * 8) * N + n0 + tx;
        t[ty + i * 8][tx] = flag ? f2b(((const float*)in)[idx]) : ((const u16*)in)[idx];
    }
    __syncthreads();
#pragma unroll
    for (int i = 0; i < 4; i++)
        outp[(size_t)(n0 + ty + i * 8) * K + k0 + tx] = t[tx][ty + i * 8];
}

// ---------------- bf16 GEMM, m97 single-buffer structure (round-0 exact): ----------------
// C[M,N] = A[M,K] * Bt[N,K]^T + bias. Tile TM x 128, BK=32, 4 waves.
// TM=128: 4x4 frags/wave (QKV, FC1). TM=64: 2x4 frags, 12 KB LDS, 2x grid for the
// N=768 GEMMs (proj/FC2) -> 4.5 blocks/CU instead of 2.25 (latency-starved regime fix).
// MODE 0: store bf16. MODE 1: bias+fast GELU, store bf16. MODE 2: f32 residual += (bias+val).
template <int MODE, int TM>
__global__ __launch_bounds__(256) void gemm_bt(const u16* __restrict__ A,
                                               const u16* __restrict__ Bt,
                                               const u16* __restrict__ bias,
                                               u16* __restrict__ outb,
                                               float* __restrict__ outf,
                                               int N, int K) {
    constexpr int MI = (TM == 128) ? 4 : 2;
    __shared__ u16 lA[TM * 32];
    __shared__ u16 lB[128 * 32];
    const int tid = threadIdx.x;
    const int wave = tid >> 6, lane = tid & 63;
    const int quad = lane >> 4, l16 = lane & 15;

    // XCD-aware bijective block remap (T1/m204): consecutive logical tiles -> same XCD L2.
    const int gx = gridDim.x;
    const int nwg = gx * gridDim.y;
    const int orig = blockIdx.y * gx + blockIdx.x;
    const int xcd = orig & 7, loc = orig >> 3;
    const int qq = nwg >> 3, rr = nwg & 7;
    const int wgid = (xcd < rr ? xcd * (qq + 1) : rr * (qq + 1) + (xcd - rr) * qq) + loc;
    const int bx = wgid % gx, by = wgid / gx;

    const int m0 = by * TM, n0 = bx << 7;
    const int wm = (wave & 1) * (TM / 2), wn = (wave >> 1) << 6;
    const int arow = lane >> 2, aseg = (lane & 3) << 3;

    f32x4 acc[MI][4] = {};

    const u16* gA = A + (size_t)(m0 + wave * 16 + arow) * K + aseg;
    const u16* gB = Bt + (size_t)(n0 + wave * 16 + arow) * K + aseg;
    const size_t skip = (size_t)64 * K; // +4 row-groups

    for (int kt = 0; kt < K; kt += 32) {
        __syncthreads();
        load_lds16(gA + kt, &lA[wave * 512 + lane * 8]);
        if constexpr (TM == 128)
            load_lds16(gA + kt + skip, &lA[(wave + 4) * 512 + lane * 8]);
        load_lds16(gB + kt, &lB[wave * 512 + lane * 8]);
        load_lds16(gB + kt + skip, &lB[(wave + 4) * 512 + lane * 8]);
        __syncthreads();
        bf16x8 af[MI], bfr[4];
#pragma unroll
        for (int i = 0; i < MI; i++)
            af[i] = *(const bf16x8*)&lA[(wm + i * 16 + l16) * 32 + quad * 8];
#pragma unroll
        for (int j = 0; j < 4; j++)
            bfr[j] = *(const bf16x8*)&lB[(wn + j * 16 + l16) * 32 + quad * 8];
#pragma unroll
        for (int i = 0; i < MI; i++)
#pragma unroll
            for (int j = 0; j < 4; j++)
                acc[i][j] = __builtin_amdgcn_mfma_f32_16x16x32_bf16(af[i], bfr[j], acc[i][j], 0, 0, 0);
    }

#pragma unroll
    for (int j = 0; j < 4; j++) {
        const int n = n0 + wn + j * 16 + l16;
        const float bv = b2f(bias[n]);
#pragma unroll
        for (int i = 0; i < MI; i++) {
            const int mrow = m0 + wm + i * 16 + quad * 4;
#pragma unroll
            for (int r = 0; r < 4; r++) {
                float v = acc[i][j][r] + bv;
                size_t idx = (size_t)(mrow + r) * N + n;
                if (MODE == 0) {
                    outb[idx] = f2b(v);
                } else if (MODE == 1) {
                    outb[idx] = f2b(gelu_fast(v));
                } else {
                    outf[idx] += v;
                }
            }
        }
    }
}

// ---------------- LayerNorm: f32 in -> bf16 out, one wave per row ----------------
__global__ __launch_bounds__(256) void ln_kernel(const float* __restrict__ x,
                                                 const u16* __restrict__ g,
                                                 const u16* __restrict__ bta,
                                                 u16* __restrict__ y) {
    const int wave = threadIdx.x >> 6, lane = threadIdx.x & 63;
    const int row = (blockIdx.x << 2) + wave;
    const float4* xr = (const float4*)(x + (size_t)row * DIM);
    float4 v[3];
    float s = 0.f, sq = 0.f;
#pragma unroll
    for (int i = 0; i < 3; i++) {
        v[i] = xr[i * 64 + lane];
        s += v[i].x + v[i].y + v[i].z + v[i].w;
        sq += v[i].x * v[i].x + v[i].y * v[i].y + v[i].z * v[i].z + v[i].w * v[i].w;
    }
#pragma unroll
    for (int off = 32; off >= 1; off >>= 1) {
        s += __shfl_xor(s, off, 64);
        sq += __shfl_xor(sq, off, 64);
    }
    const float mean = s * (1.f / DIM);
    const float var = sq * (1.f / DIM) - mean * mean;
    const float rs = rsqrtf(var + 1e-5f);
    u16* yr = y + (size_t)row * DIM;
#pragma unroll
    for (int i = 0; i < 3; i++) {
        ushort4 gg = ((const ushort4*)g)[i * 64 + lane];
        ushort4 bb = ((const ushort4*)bta)[i * 64 + lane];
        ushort4 o;
        o.x = f2b((v[i].x - mean) * rs * b2f(gg.x) + b2f(bb.x));
        o.y = f2b((v[i].y - mean) * rs * b2f(gg.y) + b2f(bb.y));
        o.z = f2b((v[i].z - mean) * rs * b2f(gg.z) + b2f(bb.z));
        o.w = f2b((v[i].w - mean) * rs * b2f(gg.w) + b2f(bb.w));
        ((ushort4*)yr)[i * 64 + lane] = o;
    }
}

// ---------------- Attention: one block per (b_local, h, 64-query tile) ----------------
template <int NJ, int JLO>
__global__ __launch_bounds__(256) void attn_kernel(const u16* __restrict__ qkv,
                                                   u16* __restrict__ out) {
    __shared__ u16 vT[64 * 392];       // V^T [d][key], padded stride 392
    __shared__ u16 pbuf[4][16 * 72];   // per-wave P chunk [m][key%64], padded stride 72
    const int bx = blockIdx.x;
    const int qt = (NJ == 24) ? (bx + (bx >= 1 ? 1 : 0)) : 1;
    const int h = blockIdx.y, b = blockIdx.z;
    const int tid = threadIdx.x, wave = tid >> 6, lane = tid & 63;
    const int quad = lane >> 4, l16 = lane & 15;
    const u16* base = qkv + (size_t)b * NTOK * (3 * DIM);

    for (int it = tid; it < NTOK * 8; it += 256) {
        const int key = it >> 3, dseg = it & 7;
        const u16* gp = base + (size_t)key * (3 * DIM) + 2 * DIM + h * HD + dseg * 8;
        ushort4 u0 = ((const ushort4*)gp)[0];
        ushort4 u1 = ((const ushort4*)gp)[1];
        u16 vals[8] = {u0.x, u0.y, u0.z, u0.w, u1.x, u1.y, u1.z, u1.w};
#pragma unroll
        for (int t = 0; t < 8; t++) {
            const int i = (t + key) & 7;
            vT[(dseg * 8 + i) * 392 + key] = vals[i];
        }
    }

    bf16x8 qf[2];
    const int qrow = qt * 64 + wave * 16 + l16;
#pragma unroll
    for (int s = 0; s < 2; s++)
        qf[s] = *(const bf16x8*)(base + (size_t)qrow * (3 * DIM) + h * HD + s * 32 + quad * 8);

    __syncthreads();

    f32x4 sacc[NJ];
#pragma unroll
    for (int j = 0; j < NJ; j++) {
        const int key = (JLO + j) * 16 + l16;
        const u16* kb = base + (size_t)key * (3 * DIM) + DIM + h * HD;
        bf16x8 k0 = *(const bf16x8*)(kb + quad * 8);
        bf16x8 k1 = *(const bf16x8*)(kb + 32 + quad * 8);
        f32x4 z = {0.f, 0.f, 0.f, 0.f};
        z = __builtin_amdgcn_mfma_f32_16x16x32_bf16(qf[0], k0, z, 0, 0, 0);
        sacc[j] = __builtin_amdgcn_mfma_f32_16x16x32_bf16(qf[1], k1, z, 0, 0, 0);
    }

    float mx[4] = {-1e30f, -1e30f, -1e30f, -1e30f};
#pragma unroll
    for (int j = 0; j < NJ; j++)
#pragma unroll
        for (int r = 0; r < 4; r++) mx[r] = fmaxf(mx[r], sacc[j][r]);
#pragma unroll
    for (int off = 1; off < 16; off <<= 1)
#pragma unroll
        for (int r = 0; r < 4; r++) mx[r] = fmaxf(mx[r], __shfl_xor(mx[r], off, 64));

    float sm[4] = {0.f, 0.f, 0.f, 0.f};
#pragma unroll
    for (int j = 0; j < NJ; j++)
#pragma unroll
        for (int r = 0; r < 4; r++) {
            float e = __expf((sacc[j][r] - mx[r]) * 0.125f);
            sacc[j][r] = e;
            sm[r] += e;
        }
#pragma unroll
    for (int off = 1; off < 16; off <<= 1)
#pragma unroll
        for (int r = 0; r < 4; r++) sm[r] += __shfl_xor(sm[r], off, 64);
    float inv[4];
#pragma unroll
    for (int r = 0; r < 4; r++) inv[r] = 1.f / sm[r];

    f32x4 oacc[4] = {};
    u16* pb = &pbuf[wave][0];
#pragma unroll
    for (int c = 0; c < NJ / 4; c++) {
        __syncthreads();
#pragma unroll
        for (int jj = 0; jj < 4; jj++) {
#pragma unroll
            for (int r = 0; r < 4; r++)
                pb[(quad * 4 + r) * 72 + jj * 16 + l16] = f2b(sacc[c * 4 + jj][r] * inv[r]);
        }
        __syncthreads();
#pragma unroll
        for (int s = 0; s < 2; s++) {
            bf16x8 pf = *(const bf16x8*)&pb[l16 * 72 + s * 32 + quad * 8];
            const int kcol = JLO * 16 + c * 64 + s * 32 + quad * 8;
#pragma unroll
            for (int jd = 0; jd < 4; jd++) {
                bf16x8 vf = *(const bf16x8*)&vT[(jd * 16 + l16) * 392 + kcol];
                oacc[jd] = __builtin_amdgcn_mfma_f32_16x16x32_bf16(pf, vf, oacc[jd], 0, 0, 0);
            }
        }
    }

    const int q = qt * 64 + wave * 16 + quad * 4;
    u16* orow = out + (size_t)(b * NTOK + q) * DIM + h * HD;
#pragma unroll
    for (int jd = 0; jd < 4; jd++)
#pragma unroll
        for (int r = 0; r < 4; r++)
            orow[(size_t)r * DIM + jd * 16 + l16] = f2b(oacc[jd][r]);
}

extern "C" void kernel_launch(void* const* d_in, const int* in_sizes, int n_in,
                              void* d_out, int out_size, void* d_ws, size_t ws_size,
                              hipStream_t stream) {
    const void* x_in   = d_in[0];
    const void* qkv_w  = d_in[1];
    const void* qkv_b  = d_in[2];
    const void* proj_w = d_in[3];
    const void* proj_b = d_in[4];
    const void* ln1_g  = d_in[5];
    const void* ln1_b  = d_in[6];
    const void* ln2_g  = d_in[7];
    const void* ln2_b  = d_in[8];
    const void* fc1_w  = d_in[9];
    const void* fc1_b  = d_in[10];
    const void* fc2_w  = d_in[11];
    const void* fc2_b  = d_in[12];

    constexpr size_t SZ_X32 = (size_t)MROWS * DIM * 4;      // 37,748,736
    constexpr size_t SZ_ABUF = (size_t)MROWS * DIM * 2;     // 18,874,368
    constexpr size_t SZ_BIG = (size_t)MROWS * MLP * 2;      // 75,497,472
    constexpr size_t SZ_WT = (size_t)(2304 * 768 + 768 * 768 + 3072 * 768 + 768 * 3072) * 2;
    constexpr size_t SZ_PAR = 262144;
    const size_t fixed = SZ_X32 + SZ_ABUF + SZ_WT + SZ_PAR + 256;

    int nc;
    if (fixed + SZ_BIG <= ws_size) nc = 1;
    else if (fixed + SZ_BIG / 2 <= ws_size) nc = 2;
    else nc = 4;
    const size_t bigsz = SZ_BIG / nc;

    char* ws = (char*)d_ws;
    float* x32 = (float*)ws;
    u16* abuf = (u16*)(ws + SZ_X32);
    u16* big = (u16*)(ws + SZ_X32 + SZ_ABUF);
    u16* wqt = (u16*)(ws + SZ_X32 + SZ_ABUF + bigsz);
    u16* wpt = wqt + 2304 * 768;
    u16* w1t = wpt + 768 * 768;
    u16* w2t = w1t + 3072 * 768;
    u16* par = w2t + 768 * 3072;
    int* flagp = (int*)((char*)(par) + SZ_PAR);

    u16* p_qkvb = par;
    u16* p_projb = p_qkvb + 12 * 2304;
    u16* p_ln1g = p_projb + 12 * 768;
    u16* p_ln1b = p_ln1g + 12 * 768;
    u16* p_ln2g = p_ln1b + 12 * 768;
    u16* p_ln2b = p_ln2g + 12 * 768;
    u16* p_fc1b = p_ln2b + 12 * 768;
    u16* p_fc2b = p_fc1b + 12 * 3072;

    const int NEL = MROWS * DIM;
    detect_kernel<<<1, 256, 0, stream>>>((const u16*)x_in, flagp);
    load_x<<<(NEL + 255) / 256, 256, 0, stream>>>(x_in, x32, NEL, flagp);
    conv_any<<<(12 * 2304 + 255) / 256, 256, 0, stream>>>(qkv_b, p_qkvb, 12 * 2304, flagp);
    conv_any<<<(12 * 768 + 255) / 256, 256, 0, stream>>>(proj_b, p_projb, 12 * 768, flagp);
    conv_any<<<(12 * 768 + 255) / 256, 256, 0, stream>>>(ln1_g, p_ln1g, 12 * 768, flagp);
    conv_any<<<(12 * 768 + 255) / 256, 256, 0, stream>>>(ln1_b, p_ln1b, 12 * 768, flagp);
    conv_any<<<(12 * 768 + 255) / 256, 256, 0, stream>>>(ln2_g, p_ln2g, 12 * 768, flagp);
    conv_any<<<(12 * 768 + 255) / 256, 256, 0, stream>>>(ln2_b, p_ln2b, 12 * 768, flagp);
    conv_any<<<(12 * 3072 + 255) / 256, 256, 0, stream>>>(fc1_b, p_fc1b, 12 * 3072, flagp);
    conv_any<<<(12 * 768 + 255) / 256, 256, 0, stream>>>(fc2_b, p_fc2b, 12 * 768, flagp);

    const int CR = MROWS / nc;  // rows per chunk (multiple of 128)
    const int CB = B_SZ / nc;   // batches per chunk

    for (int l = 0; l < 12; l++) {
        transpose_k<<<dim3(2304 / 32, 768 / 32), dim3(32, 8), 0, stream>>>(
            qkv_w, (size_t)l * DIM * 2304, wqt, DIM, 2304, flagp);
        transpose_k<<<dim3(768 / 32, 768 / 32), dim3(32, 8), 0, stream>>>(
            proj_w, (size_t)l * DIM * DIM, wpt, DIM, DIM, flagp);
        transpose_k<<<dim3(3072 / 32, 768 / 32), dim3(32, 8), 0, stream>>>(
            fc1_w, (size_t)l * DIM * MLP, w1t, DIM, MLP, flagp);
        transpose_k<<<dim3(768 / 32, 3072 / 32), dim3(32, 8), 0, stream>>>(
            fc2_w, (size_t)l * MLP * DIM, w2t, MLP, DIM, flagp);

        for (int c = 0; c < nc; c++) {
            const size_t r0 = (size_t)c * CR;
            ln_kernel<<<CR / 4, 256, 0, stream>>>(x32 + r0 * DIM, p_ln1g + l * DIM,
                                                  p_ln1b + l * DIM, abuf + r0 * DIM);
            gemm_bt<0, 128><<<dim3(2304 / 128, CR / 128), 256, 0, stream>>>(
                abuf + r0 * DIM, wqt, p_qkvb + l * 2304, big, nullptr, 2304, DIM);
            attn_kernel<24, 0><<<dim3(5, NH, CB), 256, 0, stream>>>(big, abuf + r0 * DIM);
            attn_kernel<4, 4><<<dim3(1, NH, CB), 256, 0, stream>>>(big, abuf + r0 * DIM);
            gemm_bt<2, 64><<<dim3(DIM / 128, CR / 64), 256, 0, stream>>>(
                abuf + r0 * DIM, wpt, p_projb + l * DIM, nullptr, x32 + r0 * DIM, DIM, DIM);
        }
        for (int c = 0; c < nc; c++) {
            const size_t r0 = (size_t)c * CR;
            ln_kernel<<<CR / 4, 256, 0, stream>>>(x32 + r0 * DIM, p_ln2g + l * DIM,
                                                  p_ln2b + l * DIM, abuf + r0 * DIM);
            gemm_bt<1, 128><<<dim3(MLP / 128, CR / 128), 256, 0, stream>>>(
                abuf + r0 * DIM, w1t, p_fc1b + l * MLP, big, nullptr, MLP, DIM);
            gemm_bt<2, 64><<<dim3(DIM / 128, CR / 64), 256, 0, stream>>>(
                big, w2t, p_fc2b + l * DIM, nullptr, x32 + r0 * DIM, DIM, MLP);
        }
    }
    store_out<<<(NEL + 255) / 256, 256, 0, stream>>>(x32, d_out, NEL, flagp);
}

// Round 4
// 5383.312 us; speedup vs baseline: 1.4846x; 1.0700x over previous
//
#include <hip/hip_runtime.h>
#include <cstdint>

typedef unsigned short u16;
typedef __attribute__((ext_vector_type(8))) short bf16x8;
typedef __attribute__((ext_vector_type(4))) float f32x4;

#define B_SZ 32
#define NTOK 384
#define DIM 768
#define NH 12
#define HD 64
#define MLP 3072
#define MROWS (B_SZ * NTOK) /* 12288 */

__device__ __forceinline__ float b2f(u16 h) { return __uint_as_float(((unsigned)h) << 16); }
__device__ __forceinline__ u16 f2b(float f) {
    unsigned u = __float_as_uint(f);
    unsigned r = u + 0x7fffu + ((u >> 16) & 1u); // RNE
    return (u16)(r >> 16);
}

__device__ __forceinline__ void load_lds16(const void* g, void* l) {
    __builtin_amdgcn_global_load_lds(
        (const __attribute__((address_space(1))) unsigned*)g,
        (__attribute__((address_space(3))) unsigned*)l, 16, 0, 0);
}

// fast GELU: v * sigmoid(2*0.7978845608*(v + 0.044715 v^3)); overflow-safe both tails.
__device__ __forceinline__ float gelu_fast(float v) {
    float u2 = -1.5957691216f * v * (1.0f + 0.044715f * v * v);
    return v * __builtin_amdgcn_rcpf(1.0f + __expf(u2));
}

// ---------------- dtype detect: bf16 vs f32 storage of inputs ----------------
__global__ void detect_kernel(const u16* __restrict__ x, int* __restrict__ flagp) {
    __shared__ int cnt;
    if (threadIdx.x == 0) cnt = 0;
    __syncthreads();
    int bad = 0;
    for (int i = threadIdx.x; i < 4096; i += 256) {
        int e = (x[i] >> 7) & 0xFF;
        if (e >= 0xC0) bad++;
    }
    atomicAdd(&cnt, bad);
    __syncthreads();
    if (threadIdx.x == 0) *flagp = (cnt > 4) ? 1 : 0;
}

__global__ void conv_any(const void* __restrict__ src, u16* __restrict__ dst, int n,
                         const int* __restrict__ flagp) {
    int i = blockIdx.x * 256 + threadIdx.x;
    if (i >= n) return;
    dst[i] = (*flagp) ? f2b(((const float*)src)[i]) : ((const u16*)src)[i];
}

__global__ void load_x(const void* __restrict__ src, float* __restrict__ dst, int n,
                       const int* __restrict__ flagp) {
    int i = blockIdx.x * 256 + threadIdx.x;
    if (i >= n) return;
    dst[i] = (*flagp) ? ((const float*)src)[i] : b2f(((const u16*)src)[i]);
}

__global__ void store_out(const float* __restrict__ src, void* __restrict__ dst, int n,
                          const int* __restrict__ flagp) {
    int i = blockIdx.x * 256 + threadIdx.x;
    if (i >= n) return;
    if (*flagp) ((float*)dst)[i] = src[i];
    else ((u16*)dst)[i] = f2b(src[i]);
}

// ---------------- dual-dtype weight transpose: in[K,N](+elem off) -> out[N,K] bf16 ----
__global__ __launch_bounds__(256) void transpose_k(const void* __restrict__ in, size_t ioff,
                                                   u16* __restrict__ outp, int K, int N,
                                                   const int* __restrict__ flagp) {
    __shared__ u16 t[32][33];
    const int flag = *flagp;
    const int n0 = blockIdx.x << 5, k0 = blockIdx.y << 5;
    const int tx = threadIdx.x, ty = threadIdx.y;
#pragma unroll
    for (int i = 0; i < 4; i++) {
        size_t idx = ioff + (size_t)(k0 + ty + i * 8) * N + n0 + tx;
        t[ty + i * 8][tx] = flag ? f2b(((const float*)in)[idx]) : ((const u16*)in)[idx];
    }
    __syncthreads();
#pragma unroll
    for (int i = 0; i < 4; i++)
        outp[(size_t)(n0 + ty + i * 8) * K + k0 + tx] = t[tx][ty + i * 8];
}

// ---------------- bf16 GEMM, m97 single-buffer structure, BK=64 ----------------
// C[M,N] = A[M,K] * Bt[N,K]^T + bias. Tile TM x 128, BK=64, 4 waves, K % 64 == 0.
// Per-iteration fixed cost (~720cy: stage+drain+2 barriers) amortized over 2x MFMA vs BK=32.
// LDS row stride 128B would be a 16-way bank conflict; fixed by involution swizzle
// seg' = seg ^ (row&7) applied on the PRE-SWIZZLED GLOBAL SOURCE (gload_lds dest stays
// linear, rule 21) and identically on the ds_read address -> 2-way (free, m136).
// MODE 0: store bf16. MODE 1: bias+fast GELU, store bf16. MODE 2: f32 residual += (bias+val).
template <int MODE, int TM>
__global__ __launch_bounds__(256) void gemm_bt(const u16* __restrict__ A,
                                               const u16* __restrict__ Bt,
                                               const u16* __restrict__ bias,
                                               u16* __restrict__ outb,
                                               float* __restrict__ outf,
                                               int N, int K) {
    constexpr int MI = (TM == 128) ? 4 : 2;  // 16-row fragment repeats per wave in M
    constexpr int AT = (TM == 128) ? 4 : 2;  // A-stage instrs per wave (8 rows each)
    __shared__ u16 lA[TM * 64];
    __shared__ u16 lB[128 * 64];
    const int tid = threadIdx.x;
    const int wave = tid >> 6, lane = tid & 63;
    const int quad = lane >> 4, l16 = lane & 15;

    // XCD-aware bijective block remap (T1/m204): consecutive logical tiles -> same XCD L2.
    const int gx = gridDim.x;
    const int nwg = gx * gridDim.y;
    const int orig = blockIdx.y * gx + blockIdx.x;
    const int xcd = orig & 7, loc = orig >> 3;
    const int qq = nwg >> 3, rr = nwg & 7;
    const int wgid = (xcd < rr ? xcd * (qq + 1) : rr * (qq + 1) + (xcd - rr) * qq) + loc;
    const int bx = wgid % gx, by = wgid / gx;

    const int m0 = by * TM, n0 = bx << 7;
    const int wm = (wave & 1) * (TM / 2), wn = (wave >> 1) << 6;
    const int lr = lane >> 3;                       // row-in-group 0..7
    const int swz = ((lane & 7) ^ lr) << 3;         // pre-swizzled global k-seg (u16 units)

    f32x4 acc[MI][4] = {};

    // staging base pointers (per-lane source swizzle folded in)
    const u16* gA = A + (size_t)(m0 + wave * (8 * AT) + lr) * K + swz;
    const u16* gB = Bt + (size_t)(n0 + wave * 32 + lr) * K + swz;

    for (int kt = 0; kt < K; kt += 64) {
        __syncthreads();
#pragma unroll
        for (int t = 0; t < AT; t++)
            load_lds16(gA + kt + (size_t)t * 8 * K, &lA[(wave * AT + t) * 512 + lane * 8]);
#pragma unroll
        for (int t = 0; t < 4; t++)
            load_lds16(gB + kt + (size_t)t * 8 * K, &lB[(wave * 4 + t) * 512 + lane * 8]);
        __syncthreads();
        const int xs = l16 & 7;
#pragma unroll
        for (int kk = 0; kk < 2; kk++) {
            bf16x8 af[MI], bfr[4];
            const int ksel = ((kk << 2) + quad);
#pragma unroll
            for (int i = 0; i < MI; i++)
                af[i] = *(const bf16x8*)&lA[(wm + i * 16 + l16) * 64 + ((ksel ^ xs) << 3)];
#pragma unroll
            for (int j = 0; j < 4; j++)
                bfr[j] = *(const bf16x8*)&lB[(wn + j * 16 + l16) * 64 + ((ksel ^ xs) << 3)];
#pragma unroll
            for (int i = 0; i < MI; i++)
#pragma unroll
                for (int j = 0; j < 4; j++)
                    acc[i][j] = __builtin_amdgcn_mfma_f32_16x16x32_bf16(af[i], bfr[j], acc[i][j], 0, 0, 0);
        }
    }

#pragma unroll
    for (int j = 0; j < 4; j++) {
        const int n = n0 + wn + j * 16 + l16;
        const float bv = b2f(bias[n]);
#pragma unroll
        for (int i = 0; i < MI; i++) {
            const int mrow = m0 + wm + i * 16 + quad * 4;
#pragma unroll
            for (int r = 0; r < 4; r++) {
                float v = acc[i][j][r] + bv;
                size_t idx = (size_t)(mrow + r) * N + n;
                if (MODE == 0) {
                    outb[idx] = f2b(v);
                } else if (MODE == 1) {
                    outb[idx] = f2b(gelu_fast(v));
                } else {
                    outf[idx] += v;
                }
            }
        }
    }
}

// ---------------- LayerNorm: f32 in -> bf16 out, one wave per row ----------------
__global__ __launch_bounds__(256) void ln_kernel(const float* __restrict__ x,
                                                 const u16* __restrict__ g,
                                                 const u16* __restrict__ bta,
                                                 u16* __restrict__ y) {
    const int wave = threadIdx.x >> 6, lane = threadIdx.x & 63;
    const int row = (blockIdx.x << 2) + wave;
    const float4* xr = (const float4*)(x + (size_t)row * DIM);
    float4 v[3];
    float s = 0.f, sq = 0.f;
#pragma unroll
    for (int i = 0; i < 3; i++) {
        v[i] = xr[i * 64 + lane];
        s += v[i].x + v[i].y + v[i].z + v[i].w;
        sq += v[i].x * v[i].x + v[i].y * v[i].y + v[i].z * v[i].z + v[i].w * v[i].w;
    }
#pragma unroll
    for (int off = 32; off >= 1; off >>= 1) {
        s += __shfl_xor(s, off, 64);
        sq += __shfl_xor(sq, off, 64);
    }
    const float mean = s * (1.f / DIM);
    const float var = sq * (1.f / DIM) - mean * mean;
    const float rs = rsqrtf(var + 1e-5f);
    u16* yr = y + (size_t)row * DIM;
#pragma unroll
    for (int i = 0; i < 3; i++) {
        ushort4 gg = ((const ushort4*)g)[i * 64 + lane];
        ushort4 bb = ((const ushort4*)bta)[i * 64 + lane];
        ushort4 o;
        o.x = f2b((v[i].x - mean) * rs * b2f(gg.x) + b2f(bb.x));
        o.y = f2b((v[i].y - mean) * rs * b2f(gg.y) + b2f(bb.y));
        o.z = f2b((v[i].z - mean) * rs * b2f(gg.z) + b2f(bb.z));
        o.w = f2b((v[i].w - mean) * rs * b2f(gg.w) + b2f(bb.w));
        ((ushort4*)yr)[i * 64 + lane] = o;
    }
}

// ---------------- Attention: one block per (b_local, h, 64-query tile) ----------------
template <int NJ, int JLO>
__global__ __launch_bounds__(256) void attn_kernel(const u16* __restrict__ qkv,
                                                   u16* __restrict__ out) {
    __shared__ u16 vT[64 * 392];       // V^T [d][key], padded stride 392
    __shared__ u16 pbuf[4][16 * 72];   // per-wave P chunk [m][key%64], padded stride 72
    const int bx = blockIdx.x;
    const int qt = (NJ == 24) ? (bx + (bx >= 1 ? 1 : 0)) : 1;
    const int h = blockIdx.y, b = blockIdx.z;
    const int tid = threadIdx.x, wave = tid >> 6, lane = tid & 63;
    const int quad = lane >> 4, l16 = lane & 15;
    const u16* base = qkv + (size_t)b * NTOK * (3 * DIM);

    for (int it = tid; it < NTOK * 8; it += 256) {
        const int key = it >> 3, dseg = it & 7;
        const u16* gp = base + (size_t)key * (3 * DIM) + 2 * DIM + h * HD + dseg * 8;
        ushort4 u0 = ((const ushort4*)gp)[0];
        ushort4 u1 = ((const ushort4*)gp)[1];
        u16 vals[8] = {u0.x, u0.y, u0.z, u0.w, u1.x, u1.y, u1.z, u1.w};
#pragma unroll
        for (int t = 0; t < 8; t++) {
            const int i = (t + key) & 7;
            vT[(dseg * 8 + i) * 392 + key] = vals[i];
        }
    }

    bf16x8 qf[2];
    const int qrow = qt * 64 + wave * 16 + l16;
#pragma unroll
    for (int s = 0; s < 2; s++)
        qf[s] = *(const bf16x8*)(base + (size_t)qrow * (3 * DIM) + h * HD + s * 32 + quad * 8);

    __syncthreads();

    f32x4 sacc[NJ];
#pragma unroll
    for (int j = 0; j < NJ; j++) {
        const int key = (JLO + j) * 16 + l16;
        const u16* kb = base + (size_t)key * (3 * DIM) + DIM + h * HD;
        bf16x8 k0 = *(const bf16x8*)(kb + quad * 8);
        bf16x8 k1 = *(const bf16x8*)(kb + 32 + quad * 8);
        f32x4 z = {0.f, 0.f, 0.f, 0.f};
        z = __builtin_amdgcn_mfma_f32_16x16x32_bf16(qf[0], k0, z, 0, 0, 0);
        sacc[j] = __builtin_amdgcn_mfma_f32_16x16x32_bf16(qf[1], k1, z, 0, 0, 0);
    }

    float mx[4] = {-1e30f, -1e30f, -1e30f, -1e30f};
#pragma unroll
    for (int j = 0; j < NJ; j++)
#pragma unroll
        for (int r = 0; r < 4; r++) mx[r] = fmaxf(mx[r], sacc[j][r]);
#pragma unroll
    for (int off = 1; off < 16; off <<= 1)
#pragma unroll
        for (int r = 0; r < 4; r++) mx[r] = fmaxf(mx[r], __shfl_xor(mx[r], off, 64));

    float sm[4] = {0.f, 0.f, 0.f, 0.f};
#pragma unroll
    for (int j = 0; j < NJ; j++)
#pragma unroll
        for (int r = 0; r < 4; r++) {
            float e = __expf((sacc[j][r] - mx[r]) * 0.125f);
            sacc[j][r] = e;
            sm[r] += e;
        }
#pragma unroll
    for (int off = 1; off < 16; off <<= 1)
#pragma unroll
        for (int r = 0; r < 4; r++) sm[r] += __shfl_xor(sm[r], off, 64);
    float inv[4];
#pragma unroll
    for (int r = 0; r < 4; r++) inv[r] = 1.f / sm[r];

    f32x4 oacc[4] = {};
    u16* pb = &pbuf[wave][0];
#pragma unroll
    for (int c = 0; c < NJ / 4; c++) {
        __syncthreads();
#pragma unroll
        for (int jj = 0; jj < 4; jj++) {
#pragma unroll
            for (int r = 0; r < 4; r++)
                pb[(quad * 4 + r) * 72 + jj * 16 + l16] = f2b(sacc[c * 4 + jj][r] * inv[r]);
        }
        __syncthreads();
#pragma unroll
        for (int s = 0; s < 2; s++) {
            bf16x8 pf = *(const bf16x8*)&pb[l16 * 72 + s * 32 + quad * 8];
            const int kcol = JLO * 16 + c * 64 + s * 32 + quad * 8;
#pragma unroll
            for (int jd = 0; jd < 4; jd++) {
                bf16x8 vf = *(const bf16x8*)&vT[(jd * 16 + l16) * 392 + kcol];
                oacc[jd] = __builtin_amdgcn_mfma_f32_16x16x32_bf16(pf, vf, oacc[jd], 0, 0, 0);
            }
        }
    }

    const int q = qt * 64 + wave * 16 + quad * 4;
    u16* orow = out + (size_t)(b * NTOK + q) * DIM + h * HD;
#pragma unroll
    for (int jd = 0; jd < 4; jd++)
#pragma unroll
        for (int r = 0; r < 4; r++)
            orow[(size_t)r * DIM + jd * 16 + l16] = f2b(oacc[jd][r]);
}

extern "C" void kernel_launch(void* const* d_in, const int* in_sizes, int n_in,
                              void* d_out, int out_size, void* d_ws, size_t ws_size,
                              hipStream_t stream) {
    const void* x_in   = d_in[0];
    const void* qkv_w  = d_in[1];
    const void* qkv_b  = d_in[2];
    const void* proj_w = d_in[3];
    const void* proj_b = d_in[4];
    const void* ln1_g  = d_in[5];
    const void* ln1_b  = d_in[6];
    const void* ln2_g  = d_in[7];
    const void* ln2_b  = d_in[8];
    const void* fc1_w  = d_in[9];
    const void* fc1_b  = d_in[10];
    const void* fc2_w  = d_in[11];
    const void* fc2_b  = d_in[12];

    constexpr size_t SZ_X32 = (size_t)MROWS * DIM * 4;      // 37,748,736
    constexpr size_t SZ_ABUF = (size_t)MROWS * DIM * 2;     // 18,874,368
    constexpr size_t SZ_BIG = (size_t)MROWS * MLP * 2;      // 75,497,472
    constexpr size_t SZ_WT = (size_t)(2304 * 768 + 768 * 768 + 3072 * 768 + 768 * 3072) * 2;
    constexpr size_t SZ_PAR = 262144;
    const size_t fixed = SZ_X32 + SZ_ABUF + SZ_WT + SZ_PAR + 256;

    int nc;
    if (fixed + SZ_BIG <= ws_size) nc = 1;
    else if (fixed + SZ_BIG / 2 <= ws_size) nc = 2;
    else nc = 4;
    const size_t bigsz = SZ_BIG / nc;

    char* ws = (char*)d_ws;
    float* x32 = (float*)ws;
    u16* abuf = (u16*)(ws + SZ_X32);
    u16* big = (u16*)(ws + SZ_X32 + SZ_ABUF);
    u16* wqt = (u16*)(ws + SZ_X32 + SZ_ABUF + bigsz);
    u16* wpt = wqt + 2304 * 768;
    u16* w1t = wpt + 768 * 768;
    u16* w2t = w1t + 3072 * 768;
    u16* par = w2t + 768 * 3072;
    int* flagp = (int*)((char*)(par) + SZ_PAR);

    u16* p_qkvb = par;
    u16* p_projb = p_qkvb + 12 * 2304;
    u16* p_ln1g = p_projb + 12 * 768;
    u16* p_ln1b = p_ln1g + 12 * 768;
    u16* p_ln2g = p_ln1b + 12 * 768;
    u16* p_ln2b = p_ln2g + 12 * 768;
    u16* p_fc1b = p_ln2b + 12 * 768;
    u16* p_fc2b = p_fc1b + 12 * 3072;

    const int NEL = MROWS * DIM;
    detect_kernel<<<1, 256, 0, stream>>>((const u16*)x_in, flagp);
    load_x<<<(NEL + 255) / 256, 256, 0, stream>>>(x_in, x32, NEL, flagp);
    conv_any<<<(12 * 2304 + 255) / 256, 256, 0, stream>>>(qkv_b, p_qkvb, 12 * 2304, flagp);
    conv_any<<<(12 * 768 + 255) / 256, 256, 0, stream>>>(proj_b, p_projb, 12 * 768, flagp);
    conv_any<<<(12 * 768 + 255) / 256, 256, 0, stream>>>(ln1_g, p_ln1g, 12 * 768, flagp);
    conv_any<<<(12 * 768 + 255) / 256, 256, 0, stream>>>(ln1_b, p_ln1b, 12 * 768, flagp);
    conv_any<<<(12 * 768 + 255) / 256, 256, 0, stream>>>(ln2_g, p_ln2g, 12 * 768, flagp);
    conv_any<<<(12 * 768 + 255) / 256, 256, 0, stream>>>(ln2_b, p_ln2b, 12 * 768, flagp);
    conv_any<<<(12 * 3072 + 255) / 256, 256, 0, stream>>>(fc1_b, p_fc1b, 12 * 3072, flagp);
    conv_any<<<(12 * 768 + 255) / 256, 256, 0, stream>>>(fc2_b, p_fc2b, 12 * 768, flagp);

    const int CR = MROWS / nc;  // rows per chunk (multiple of 128)
    const int CB = B_SZ / nc;   // batches per chunk

    for (int l = 0; l < 12; l++) {
        transpose_k<<<dim3(2304 / 32, 768 / 32), dim3(32, 8), 0, stream>>>(
            qkv_w, (size_t)l * DIM * 2304, wqt, DIM, 2304, flagp);
        transpose_k<<<dim3(768 / 32, 768 / 32), dim3(32, 8), 0, stream>>>(
            proj_w, (size_t)l * DIM * DIM, wpt, DIM, DIM, flagp);
        transpose_k<<<dim3(3072 / 32, 768 / 32), dim3(32, 8), 0, stream>>>(
            fc1_w, (size_t)l * DIM * MLP, w1t, DIM, MLP, flagp);
        transpose_k<<<dim3(768 / 32, 3072 / 32), dim3(32, 8), 0, stream>>>(
            fc2_w, (size_t)l * MLP * DIM, w2t, MLP, DIM, flagp);

        for (int c = 0; c < nc; c++) {
            const size_t r0 = (size_t)c * CR;
            ln_kernel<<<CR / 4, 256, 0, stream>>>(x32 + r0 * DIM, p_ln1g + l * DIM,
                                                  p_ln1b + l * DIM, abuf + r0 * DIM);
            gemm_bt<0, 128><<<dim3(2304 / 128, CR / 128), 256, 0, stream>>>(
                abuf + r0 * DIM, wqt, p_qkvb + l * 2304, big, nullptr, 2304, DIM);
            attn_kernel<24, 0><<<dim3(5, NH, CB), 256, 0, stream>>>(big, abuf + r0 * DIM);
            attn_kernel<4, 4><<<dim3(1, NH, CB), 256, 0, stream>>>(big, abuf + r0 * DIM);
            gemm_bt<2, 64><<<dim3(DIM / 128, CR / 64), 256, 0, stream>>>(
                abuf + r0 * DIM, wpt, p_projb + l * DIM, nullptr, x32 + r0 * DIM, DIM, DIM);
        }
        for (int c = 0; c < nc; c++) {
            const size_t r0 = (size_t)c * CR;
            ln_kernel<<<CR / 4, 256, 0, stream>>>(x32 + r0 * DIM, p_ln2g + l * DIM,
                                                  p_ln2b + l * DIM, abuf + r0 * DIM);
            gemm_bt<1, 128><<<dim3(MLP / 128, CR / 128), 256, 0, stream>>>(
                abuf + r0 * DIM, w1t, p_fc1b + l * MLP, big, nullptr, MLP, DIM);
            gemm_bt<2, 64><<<dim3(DIM / 128, CR / 64), 256, 0, stream>>>(
                big, w2t, p_fc2b + l * DIM, nullptr, x32 + r0 * DIM, DIM, MLP);
        }
    }
    store_out<<<(NEL + 255) / 256, 256, 0, stream>>>(x32, d_out, NEL, flagp);
}

// Round 5
// 5187.260 us; speedup vs baseline: 1.5407x; 1.0378x over previous
//
#include <hip/hip_runtime.h>
#include <cstdint>

typedef unsigned short u16;
typedef __attribute__((ext_vector_type(8))) short bf16x8;
typedef __attribute__((ext_vector_type(4))) float f32x4;

#define B_SZ 32
#define NTOK 384
#define DIM 768
#define NH 12
#define HD 64
#define MLP 3072
#define MROWS (B_SZ * NTOK) /* 12288 */

__device__ __forceinline__ float b2f(u16 h) { return __uint_as_float(((unsigned)h) << 16); }
__device__ __forceinline__ u16 f2b(float f) {
    unsigned u = __float_as_uint(f);
    unsigned r = u + 0x7fffu + ((u >> 16) & 1u); // RNE
    return (u16)(r >> 16);
}

__device__ __forceinline__ void load_lds16(const void* g, void* l) {
    __builtin_amdgcn_global_load_lds(
        (const __attribute__((address_space(1))) unsigned*)g,
        (__attribute__((address_space(3))) unsigned*)l, 16, 0, 0);
}

// fast GELU: v * sigmoid(2*0.7978845608*(v + 0.044715 v^3)); overflow-safe both tails.
__device__ __forceinline__ float gelu_fast(float v) {
    float u2 = -1.5957691216f * v * (1.0f + 0.044715f * v * v);
    return v * __builtin_amdgcn_rcpf(1.0f + __expf(u2));
}

// ---------------- dtype detect: bf16 vs f32 storage of inputs ----------------
__global__ void detect_kernel(const u16* __restrict__ x, int* __restrict__ flagp) {
    __shared__ int cnt;
    if (threadIdx.x == 0) cnt = 0;
    __syncthreads();
    int bad = 0;
    for (int i = threadIdx.x; i < 4096; i += 256) {
        int e = (x[i] >> 7) & 0xFF;
        if (e >= 0xC0) bad++;
    }
    atomicAdd(&cnt, bad);
    __syncthreads();
    if (threadIdx.x == 0) *flagp = (cnt > 4) ? 1 : 0;
}

__global__ void conv_any(const void* __restrict__ src, u16* __restrict__ dst, int n,
                         const int* __restrict__ flagp) {
    int i = blockIdx.x * 256 + threadIdx.x;
    if (i >= n) return;
    dst[i] = (*flagp) ? f2b(((const float*)src)[i]) : ((const u16*)src)[i];
}

__global__ void load_x(const void* __restrict__ src, float* __restrict__ dst, int n,
                       const int* __restrict__ flagp) {
    int i = blockIdx.x * 256 + threadIdx.x;
    if (i >= n) return;
    dst[i] = (*flagp) ? ((const float*)src)[i] : b2f(((const u16*)src)[i]);
}

__global__ void store_out(const float* __restrict__ src, void* __restrict__ dst, int n,
                          const int* __restrict__ flagp) {
    int i = blockIdx.x * 256 + threadIdx.x;
    if (i >= n) return;
    if (*flagp) ((float*)dst)[i] = src[i];
    else ((u16*)dst)[i] = f2b(src[i]);
}

// ---------------- dual-dtype weight transpose: in[K,N](+elem off) -> out[N,K] bf16 ----
__global__ __launch_bounds__(256) void transpose_k(const void* __restrict__ in, size_t ioff,
                                                   u16* __restrict__ outp, int K, int N,
                                                   const int* __restrict__ flagp) {
    __shared__ u16 t[32][33];
    const int flag = *flagp;
    const int n0 = blockIdx.x << 5, k0 = blockIdx.y << 5;
    const int tx = threadIdx.x, ty = threadIdx.y;
#pragma unroll
    for (int i = 0; i < 4; i++) {
        size_t idx = ioff + (size_t)(k0 + ty + i * 8) * N + n0 + tx;
        t[ty + i * 8][tx] = flag ? f2b(((const float*)in)[idx]) : ((const u16*)in)[idx];
    }
    __syncthreads();
#pragma unroll
    for (int i = 0; i < 4; i++)
        outp[(size_t)(n0 + ty + i * 8) * K + k0 + tx] = t[tx][ty + i * 8];
}

// ---------------- bf16 GEMM, m97 single-buffer structure, BK=64 ----------------
// C[M,N] = A[M,K] * Bt[N,K]^T + bias. Tile TM x 128, BK=64, 4 waves, K % 64 == 0.
// LDS row stride 128B -> involution swizzle seg' = seg ^ (row&7) on pre-swizzled global
// source (gload_lds dest linear, rule 21) + same XOR on ds_read -> 2-way (free).
// MODE 0: store bf16. MODE 1: bias+fast GELU, store bf16. MODE 2: f32 residual += (bias+val).
template <int MODE, int TM>
__global__ __launch_bounds__(256) void gemm_bt(const u16* __restrict__ A,
                                               const u16* __restrict__ Bt,
                                               const u16* __restrict__ bias,
                                               u16* __restrict__ outb,
                                               float* __restrict__ outf,
                                               int N, int K) {
    constexpr int MI = (TM == 128) ? 4 : 2;  // 16-row fragment repeats per wave in M
    constexpr int AT = (TM == 128) ? 4 : 2;  // A-stage instrs per wave (8 rows each)
    __shared__ u16 lA[TM * 64];
    __shared__ u16 lB[128 * 64];
    const int tid = threadIdx.x;
    const int wave = tid >> 6, lane = tid & 63;
    const int quad = lane >> 4, l16 = lane & 15;

    // XCD-aware bijective block remap (T1/m204): consecutive logical tiles -> same XCD L2.
    const int gx = gridDim.x;
    const int nwg = gx * gridDim.y;
    const int orig = blockIdx.y * gx + blockIdx.x;
    const int xcd = orig & 7, loc = orig >> 3;
    const int qq = nwg >> 3, rr = nwg & 7;
    const int wgid = (xcd < rr ? xcd * (qq + 1) : rr * (qq + 1) + (xcd - rr) * qq) + loc;
    const int bx = wgid % gx, by = wgid / gx;

    const int m0 = by * TM, n0 = bx << 7;
    const int wm = (wave & 1) * (TM / 2), wn = (wave >> 1) << 6;
    const int lr = lane >> 3;                       // row-in-group 0..7
    const int swz = ((lane & 7) ^ lr) << 3;         // pre-swizzled global k-seg (u16 units)

    f32x4 acc[MI][4] = {};

    const u16* gA = A + (size_t)(m0 + wave * (8 * AT) + lr) * K + swz;
    const u16* gB = Bt + (size_t)(n0 + wave * 32 + lr) * K + swz;

    for (int kt = 0; kt < K; kt += 64) {
        __syncthreads();
#pragma unroll
        for (int t = 0; t < AT; t++)
            load_lds16(gA + kt + (size_t)t * 8 * K, &lA[(wave * AT + t) * 512 + lane * 8]);
#pragma unroll
        for (int t = 0; t < 4; t++)
            load_lds16(gB + kt + (size_t)t * 8 * K, &lB[(wave * 4 + t) * 512 + lane * 8]);
        __syncthreads();
        const int xs = l16 & 7;
#pragma unroll
        for (int kk = 0; kk < 2; kk++) {
            bf16x8 af[MI], bfr[4];
            const int ksel = ((kk << 2) + quad);
#pragma unroll
            for (int i = 0; i < MI; i++)
                af[i] = *(const bf16x8*)&lA[(wm + i * 16 + l16) * 64 + ((ksel ^ xs) << 3)];
#pragma unroll
            for (int j = 0; j < 4; j++)
                bfr[j] = *(const bf16x8*)&lB[(wn + j * 16 + l16) * 64 + ((ksel ^ xs) << 3)];
#pragma unroll
            for (int i = 0; i < MI; i++)
#pragma unroll
                for (int j = 0; j < 4; j++)
                    acc[i][j] = __builtin_amdgcn_mfma_f32_16x16x32_bf16(af[i], bfr[j], acc[i][j], 0, 0, 0);
        }
    }

#pragma unroll
    for (int j = 0; j < 4; j++) {
        const int n = n0 + wn + j * 16 + l16;
        const float bv = b2f(bias[n]);
#pragma unroll
        for (int i = 0; i < MI; i++) {
            const int mrow = m0 + wm + i * 16 + quad * 4;
#pragma unroll
            for (int r = 0; r < 4; r++) {
                float v = acc[i][j][r] + bv;
                size_t idx = (size_t)(mrow + r) * N + n;
                if (MODE == 0) {
                    outb[idx] = f2b(v);
                } else if (MODE == 1) {
                    outb[idx] = f2b(gelu_fast(v));
                } else {
                    outf[idx] += v;
                }
            }
        }
    }
}

// ---------------- LayerNorm: f32 in -> bf16 out, one wave per row ----------------
__global__ __launch_bounds__(256) void ln_kernel(const float* __restrict__ x,
                                                 const u16* __restrict__ g,
                                                 const u16* __restrict__ bta,
                                                 u16* __restrict__ y) {
    const int wave = threadIdx.x >> 6, lane = threadIdx.x & 63;
    const int row = (blockIdx.x << 2) + wave;
    const float4* xr = (const float4*)(x + (size_t)row * DIM);
    float4 v[3];
    float s = 0.f, sq = 0.f;
#pragma unroll
    for (int i = 0; i < 3; i++) {
        v[i] = xr[i * 64 + lane];
        s += v[i].x + v[i].y + v[i].z + v[i].w;
        sq += v[i].x * v[i].x + v[i].y * v[i].y + v[i].z * v[i].z + v[i].w * v[i].w;
    }
#pragma unroll
    for (int off = 32; off >= 1; off >>= 1) {
        s += __shfl_xor(s, off, 64);
        sq += __shfl_xor(sq, off, 64);
    }
    const float mean = s * (1.f / DIM);
    const float var = sq * (1.f / DIM) - mean * mean;
    const float rs = rsqrtf(var + 1e-5f);
    u16* yr = y + (size_t)row * DIM;
#pragma unroll
    for (int i = 0; i < 3; i++) {
        ushort4 gg = ((const ushort4*)g)[i * 64 + lane];
        ushort4 bb = ((const ushort4*)bta)[i * 64 + lane];
        ushort4 o;
        o.x = f2b((v[i].x - mean) * rs * b2f(gg.x) + b2f(bb.x));
        o.y = f2b((v[i].y - mean) * rs * b2f(gg.y) + b2f(bb.y));
        o.z = f2b((v[i].z - mean) * rs * b2f(gg.z) + b2f(bb.z));
        o.w = f2b((v[i].w - mean) * rs * b2f(gg.w) + b2f(bb.w));
        ((ushort4*)yr)[i * 64 + lane] = o;
    }
}

// ---------------- Attention: one block per (b_local, h, 64-query tile) ----------------
// NJ=24: full tiles (qt in {0,2,3,4,5}); XCD-aware assignment puts the 5 qt-blocks of one
// (b,h) on the SAME XCD (linear dispatch id round-robins XCDs by id&7) -> K/V L2-local.
// NJ=4: inner tile (qt=1), stages ONLY keys 64..128 (1/6 the staging, 19KB LDS).
// Staging write rotation (t+kk+dseg)&7: dseg enters the bank via 4i (row-stride*8 = 0 mod
// 128B so plain dseg cancels) -> <=2-way. pbuf stride 76: write banks 24*quad+l16/2
// disjoint -> conflict-free. pbuf is WAVE-PRIVATE: no __syncthreads in the PV loop
// (intra-wave LDS ordering via compiler lgkmcnt).
template <int NJ, int JLO>
__global__ __launch_bounds__(256) void attn_kernel(const u16* __restrict__ qkv,
                                                   u16* __restrict__ out) {
    constexpr int K0 = JLO * 16;          // first staged key (0 or 64)
    constexpr int NKEY = NJ * 16;         // staged keys (384 or 64)
    constexpr int VSTR = NKEY + 8;        // 392 or 72
    __shared__ u16 vT[64 * VSTR];         // V^T [d][staged key]
    __shared__ u16 pbuf[4][16 * 76];      // per-wave P chunk [m][key%64]
    const int tid = threadIdx.x, wave = tid >> 6, lane = tid & 63;
    const int quad = lane >> 4, l16 = lane & 15;

    int qt, h, b;
    if (NJ == 24) {
        const int id = blockIdx.x + 5 * (blockIdx.y + 12 * blockIdx.z);
        const int xcd = id & 7, slot = id >> 3;
        const int ppx = (int)(gridDim.x * gridDim.y * gridDim.z) >> 3; // slots per XCD
        const int s5 = slot / 5;
        const int pair = xcd * (ppx / 5) + s5;   // (b,h) pair, 5 co-XCD blocks share it
        const int qi = slot - 5 * s5;
        qt = qi + (qi >= 1 ? 1 : 0);             // {0,2,3,4,5}
        h = pair % 12;
        b = pair / 12;
    } else {
        qt = 1; h = blockIdx.y; b = blockIdx.z;
    }
    const u16* base = qkv + (size_t)b * NTOK * (3 * DIM);

    // stage V^T for keys [K0, K0+NKEY) (16B loads, bank-spread rotated scatter)
    for (int it = tid; it < NKEY * 8; it += 256) {
        const int kk = it >> 3, dseg = it & 7;
        const u16* gp = base + (size_t)(K0 + kk) * (3 * DIM) + 2 * DIM + h * HD + dseg * 8;
        ushort4 u0 = ((const ushort4*)gp)[0];
        ushort4 u1 = ((const ushort4*)gp)[1];
        u16 vals[8] = {u0.x, u0.y, u0.z, u0.w, u1.x, u1.y, u1.z, u1.w};
#pragma unroll
        for (int t = 0; t < 8; t++) {
            const int i = (t + kk + dseg) & 7;
            vT[(dseg * 8 + i) * VSTR + kk] = vals[i];
        }
    }

    // Q fragments (A-operand layout), straight from global
    bf16x8 qf[2];
    const int qrow = qt * 64 + wave * 16 + l16;
#pragma unroll
    for (int s = 0; s < 2; s++)
        qf[s] = *(const bf16x8*)(base + (size_t)qrow * (3 * DIM) + h * HD + s * 32 + quad * 8);

    __syncthreads();  // vT visible to all waves

    // S = Q K^T over NJ key tiles (K fragments straight from global, L2-served)
    f32x4 sacc[NJ];
#pragma unroll
    for (int j = 0; j < NJ; j++) {
        const int key = (JLO + j) * 16 + l16;
        const u16* kb = base + (size_t)key * (3 * DIM) + DIM + h * HD;
        bf16x8 k0 = *(const bf16x8*)(kb + quad * 8);
        bf16x8 k1 = *(const bf16x8*)(kb + 32 + quad * 8);
        f32x4 z = {0.f, 0.f, 0.f, 0.f};
        z = __builtin_amdgcn_mfma_f32_16x16x32_bf16(qf[0], k0, z, 0, 0, 0);
        sacc[j] = __builtin_amdgcn_mfma_f32_16x16x32_bf16(qf[1], k1, z, 0, 0, 0);
    }

    // softmax over rows (row m = quad*4+r lives in the 16 lanes of this quad)
    float mx[4] = {-1e30f, -1e30f, -1e30f, -1e30f};
#pragma unroll
    for (int j = 0; j < NJ; j++)
#pragma unroll
        for (int r = 0; r < 4; r++) mx[r] = fmaxf(mx[r], sacc[j][r]);
#pragma unroll
    for (int off = 1; off < 16; off <<= 1)
#pragma unroll
        for (int r = 0; r < 4; r++) mx[r] = fmaxf(mx[r], __shfl_xor(mx[r], off, 64));

    float sm[4] = {0.f, 0.f, 0.f, 0.f};
#pragma unroll
    for (int j = 0; j < NJ; j++)
#pragma unroll
        for (int r = 0; r < 4; r++) {
            float e = __expf((sacc[j][r] - mx[r]) * 0.125f);
            sacc[j][r] = e;
            sm[r] += e;
        }
#pragma unroll
    for (int off = 1; off < 16; off <<= 1)
#pragma unroll
        for (int r = 0; r < 4; r++) sm[r] += __shfl_xor(sm[r], off, 64);
    float inv[4];
#pragma unroll
    for (int r = 0; r < 4; r++) inv[r] = 1.f / sm[r];

    // O = P V, per 64-key chunk: P (D-layout regs) -> wave-private LDS -> A-layout frags
    f32x4 oacc[4] = {};
    u16* pb = &pbuf[wave][0];
#pragma unroll
    for (int c = 0; c < NJ / 4; c++) {
#pragma unroll
        for (int jj = 0; jj < 4; jj++) {
#pragma unroll
            for (int r = 0; r < 4; r++)
                pb[(quad * 4 + r) * 76 + jj * 16 + l16] = f2b(sacc[c * 4 + jj][r] * inv[r]);
        }
        // no barrier: pbuf[wave] is wave-private; lgkmcnt orders write->read
#pragma unroll
        for (int s = 0; s < 2; s++) {
            bf16x8 pf = *(const bf16x8*)&pb[l16 * 76 + s * 32 + quad * 8];
            const int kc = c * 64 + s * 32 + quad * 8;   // staged-key index
#pragma unroll
            for (int jd = 0; jd < 4; jd++) {
                bf16x8 vf = *(const bf16x8*)&vT[(jd * 16 + l16) * VSTR + kc];
                oacc[jd] = __builtin_amdgcn_mfma_f32_16x16x32_bf16(pf, vf, oacc[jd], 0, 0, 0);
            }
        }
    }

    const int q = qt * 64 + wave * 16 + quad * 4;
    u16* orow = out + (size_t)(b * NTOK + q) * DIM + h * HD;
#pragma unroll
    for (int jd = 0; jd < 4; jd++)
#pragma unroll
        for (int r = 0; r < 4; r++)
            orow[(size_t)r * DIM + jd * 16 + l16] = f2b(oacc[jd][r]);
}

extern "C" void kernel_launch(void* const* d_in, const int* in_sizes, int n_in,
                              void* d_out, int out_size, void* d_ws, size_t ws_size,
                              hipStream_t stream) {
    const void* x_in   = d_in[0];
    const void* qkv_w  = d_in[1];
    const void* qkv_b  = d_in[2];
    const void* proj_w = d_in[3];
    const void* proj_b = d_in[4];
    const void* ln1_g  = d_in[5];
    const void* ln1_b  = d_in[6];
    const void* ln2_g  = d_in[7];
    const void* ln2_b  = d_in[8];
    const void* fc1_w  = d_in[9];
    const void* fc1_b  = d_in[10];
    const void* fc2_w  = d_in[11];
    const void* fc2_b  = d_in[12];

    constexpr size_t SZ_X32 = (size_t)MROWS * DIM * 4;      // 37,748,736
    constexpr size_t SZ_ABUF = (size_t)MROWS * DIM * 2;     // 18,874,368
    constexpr size_t SZ_BIG = (size_t)MROWS * MLP * 2;      // 75,497,472
    constexpr size_t SZ_WT = (size_t)(2304 * 768 + 768 * 768 + 3072 * 768 + 768 * 3072) * 2;
    constexpr size_t SZ_PAR = 262144;
    const size_t fixed = SZ_X32 + SZ_ABUF + SZ_WT + SZ_PAR + 256;

    int nc;
    if (fixed + SZ_BIG <= ws_size) nc = 1;
    else if (fixed + SZ_BIG / 2 <= ws_size) nc = 2;
    else nc = 4;
    const size_t bigsz = SZ_BIG / nc;

    char* ws = (char*)d_ws;
    float* x32 = (float*)ws;
    u16* abuf = (u16*)(ws + SZ_X32);
    u16* big = (u16*)(ws + SZ_X32 + SZ_ABUF);
    u16* wqt = (u16*)(ws + SZ_X32 + SZ_ABUF + bigsz);
    u16* wpt = wqt + 2304 * 768;
    u16* w1t = wpt + 768 * 768;
    u16* w2t = w1t + 3072 * 768;
    u16* par = w2t + 768 * 3072;
    int* flagp = (int*)((char*)(par) + SZ_PAR);

    u16* p_qkvb = par;
    u16* p_projb = p_qkvb + 12 * 2304;
    u16* p_ln1g = p_projb + 12 * 768;
    u16* p_ln1b = p_ln1g + 12 * 768;
    u16* p_ln2g = p_ln1b + 12 * 768;
    u16* p_ln2b = p_ln2g + 12 * 768;
    u16* p_fc1b = p_ln2b + 12 * 768;
    u16* p_fc2b = p_fc1b + 12 * 3072;

    const int NEL = MROWS * DIM;
    detect_kernel<<<1, 256, 0, stream>>>((const u16*)x_in, flagp);
    load_x<<<(NEL + 255) / 256, 256, 0, stream>>>(x_in, x32, NEL, flagp);
    conv_any<<<(12 * 2304 + 255) / 256, 256, 0, stream>>>(qkv_b, p_qkvb, 12 * 2304, flagp);
    conv_any<<<(12 * 768 + 255) / 256, 256, 0, stream>>>(proj_b, p_projb, 12 * 768, flagp);
    conv_any<<<(12 * 768 + 255) / 256, 256, 0, stream>>>(ln1_g, p_ln1g, 12 * 768, flagp);
    conv_any<<<(12 * 768 + 255) / 256, 256, 0, stream>>>(ln1_b, p_ln1b, 12 * 768, flagp);
    conv_any<<<(12 * 768 + 255) / 256, 256, 0, stream>>>(ln2_g, p_ln2g, 12 * 768, flagp);
    conv_any<<<(12 * 768 + 255) / 256, 256, 0, stream>>>(ln2_b, p_ln2b, 12 * 768, flagp);
    conv_any<<<(12 * 3072 + 255) / 256, 256, 0, stream>>>(fc1_b, p_fc1b, 12 * 3072, flagp);
    conv_any<<<(12 * 768 + 255) / 256, 256, 0, stream>>>(fc2_b, p_fc2b, 12 * 768, flagp);

    const int CR = MROWS / nc;  // rows per chunk (multiple of 128)
    const int CB = B_SZ / nc;   // batches per chunk

    for (int l = 0; l < 12; l++) {
        transpose_k<<<dim3(2304 / 32, 768 / 32), dim3(32, 8), 0, stream>>>(
            qkv_w, (size_t)l * DIM * 2304, wqt, DIM, 2304, flagp);
        transpose_k<<<dim3(768 / 32, 768 / 32), dim3(32, 8), 0, stream>>>(
            proj_w, (size_t)l * DIM * DIM, wpt, DIM, DIM, flagp);
        transpose_k<<<dim3(3072 / 32, 768 / 32), dim3(32, 8), 0, stream>>>(
            fc1_w, (size_t)l * DIM * MLP, w1t, DIM, MLP, flagp);
        transpose_k<<<dim3(768 / 32, 3072 / 32), dim3(32, 8), 0, stream>>>(
            fc2_w, (size_t)l * MLP * DIM, w2t, MLP, DIM, flagp);

        for (int c = 0; c < nc; c++) {
            const size_t r0 = (size_t)c * CR;
            ln_kernel<<<CR / 4, 256, 0, stream>>>(x32 + r0 * DIM, p_ln1g + l * DIM,
                                                  p_ln1b + l * DIM, abuf + r0 * DIM);
            gemm_bt<0, 128><<<dim3(2304 / 128, CR / 128), 256, 0, stream>>>(
                abuf + r0 * DIM, wqt, p_qkvb + l * 2304, big, nullptr, 2304, DIM);
            attn_kernel<24, 0><<<dim3(5, NH, CB), 256, 0, stream>>>(big, abuf + r0 * DIM);
            attn_kernel<4, 4><<<dim3(1, NH, CB), 256, 0, stream>>>(big, abuf + r0 * DIM);
            gemm_bt<2, 64><<<dim3(DIM / 128, CR / 64), 256, 0, stream>>>(
                abuf + r0 * DIM, wpt, p_projb + l * DIM, nullptr, x32 + r0 * DIM, DIM, DIM);
        }
        for (int c = 0; c < nc; c++) {
            const size_t r0 = (size_t)c * CR;
            ln_kernel<<<CR / 4, 256, 0, stream>>>(x32 + r0 * DIM, p_ln2g + l * DIM,
                                                  p_ln2b + l * DIM, abuf + r0 * DIM);
            gemm_bt<1, 128><<<dim3(MLP / 128, CR / 128), 256, 0, stream>>>(
                abuf + r0 * DIM, w1t, p_fc1b + l * MLP, big, nullptr, MLP, DIM);
            gemm_bt<2, 64><<<dim3(DIM / 128, CR / 64), 256, 0, stream>>>(
                big, w2t, p_fc2b + l * DIM, nullptr, x32 + r0 * DIM, DIM, MLP);
        }
    }
    store_out<<<(NEL + 255) / 256, 256, 0, stream>>>(x32, d_out, NEL, flagp);
}